// Round 7
// baseline (266.134 us; speedup 1.0000x reference)
//
#include <hip/hip_runtime.h>
#include <hip/hip_bf16.h>
#include <cmath>

// I/O: all inputs float32 (per reference setup_inputs), output float32.
// Internal compute: bf16 MFMA with fp32 accumulation.
//
// Workspace layout (64 MB total):
//  [0,16M)   WqkvT  [4096][2048] bf16   (rows: 0-2047 WqT, 2048-3071 WkT, 3072-4095 WvT)
//  [16,24M)  WoT    [2048][2048] bf16
//  [24,40M)  QKVraw [2048][4096] bf16
//  [40,48M)  Qn     [2048][2048] bf16   (post rms+rope, pre-scaled by QK_SCALE*log2e)
//  [48,52M)  Kn     [2048][1024] bf16
//  [52,56M)  Vt     [1024][2048] bf16   ([hkv*128 d][s])
//  [56,64M)  hsb    [2048][2048] bf16   (live: kernels 1-2)   }  overlaid,
//  [56,64M)  AT     [2048][2048] bf16   (live: kernels 4-5)   }  disjoint liveness
//
// R7 == R6 resubmitted (R6 bench was an infra failure, no counters).
// GEMMs rebuilt as A-in-registers / B-in-LDS hybrid.  Rationale: at
// 46us gemm1's CU-level LDS traffic (reads 128KB + gld_lds writes 64KB per
// BK-pair) is ~65% of the b128 ceiling -- the dominant pipe; A-fragments
// have no useful cross-wave reuse (wave pairs share rows, 2nd reader is
// L1-hit), so A skips LDS entirely: per-BK fragments are loaded
// global->VGPR one BK ahead (aC/aN ping-pong, statically indexed), hidden
// under the ~3450-cyc body.  LDS bytes/BK halve; B staging/swizzle and the
// proven 2-block/CU 2-phase structure unchanged.  trans_cvt/rms_vt/attn
// identical to R5 (u32-pair conflict-free transposes, attn XCD head map).

typedef __bf16 bf16x8 __attribute__((ext_vector_type(8)));
typedef float  f32x4  __attribute__((ext_vector_type(4)));

#define S_LEN    2048
#define NH       16
#define NKV      8
#define HDIM     128
#define WIN      1024
// QK_SCALE * log2(e): scores computed directly in log2 domain -> exp2
#define QK_SCALE_L2E 0.12751744595f
#define RMS_EPS  1e-6f

__device__ __forceinline__ void gld16(void* lds, const void* g) {
    __builtin_amdgcn_global_load_lds(
        (const __attribute__((address_space(1))) unsigned int*)g,
        (__attribute__((address_space(3))) unsigned int*)lds, 16, 0, 0);
}

__device__ __forceinline__ unsigned short f2bu(float x) {
    __hip_bfloat16 h = __float2bfloat16(x);
    return *(unsigned short*)&h;
}

// ---------------------------------------------------------------------------
// Fused: weight transpose + f32->bf16 (blocks 0..3071)  AND
//        hidden_states f32->bf16 convert (blocks 3072..5119).
// Conflict-free u32-pair transpose tile (see R5 notes).
// ---------------------------------------------------------------------------
__global__ __launch_bounds__(256) void trans_cvt_kernel(
    const float* __restrict__ Wq, const float* __restrict__ Wk,
    const float* __restrict__ Wv, const float* __restrict__ Wo,
    const float* __restrict__ hs,
    __hip_bfloat16* __restrict__ WqkvT, __hip_bfloat16* __restrict__ WoT,
    __hip_bfloat16* __restrict__ hsb)
{
    __shared__ __attribute__((aligned(16))) unsigned tile32[64][37];
    int id = blockIdx.x;
    if (id >= 3072) {   // ---- hidden_states convert: 8 elems/thread ----
        size_t i = ((size_t)(id - 3072) * 256 + threadIdx.x) * 8;
        float4 a = *(const float4*)(hs + i);
        float4 b = *(const float4*)(hs + i + 4);
        unsigned short u[8] = { f2bu(a.x), f2bu(a.y), f2bu(a.z), f2bu(a.w),
                                f2bu(b.x), f2bu(b.y), f2bu(b.z), f2bu(b.w) };
        *(uint4*)(hsb + i) = *(uint4*)u;
        return;
    }
    const float* src; __hip_bfloat16* dst; int N, kt, nt;
    if (id < 1024)      { src = Wq; dst = WqkvT;                          N = 2048; kt = id >> 5;          nt = id & 31; }
    else if (id < 1536) { src = Wk; dst = WqkvT + (size_t)2048*2048;      N = 1024; kt = (id-1024) >> 4;   nt = (id-1024) & 15; }
    else if (id < 2048) { src = Wv; dst = WqkvT + (size_t)3072*2048;      N = 1024; kt = (id-1536) >> 4;   nt = (id-1536) & 15; }
    else                { src = Wo; dst = WoT;                            N = 2048; kt = (id-2048) >> 5;   nt = (id-2048) & 31; }
    int k0 = kt * 64, n0 = nt * 64;
    int tid = threadIdx.x;
#pragma unroll
    for (int p = 0; p < 2; ++p) {           // phase 1: read rows, cvt, swizzled store
        int c = p*256 + tid; int r = c >> 3, cc = (c & 7) * 8;
        const float* s = src + (size_t)(k0 + r)*N + n0 + cc;
        float4 a = *(const float4*)s;
        float4 b = *(const float4*)(s + 4);
        unsigned w0 = f2bu(a.x) | ((unsigned)f2bu(a.y) << 16);
        unsigned w1 = f2bu(a.z) | ((unsigned)f2bu(a.w) << 16);
        unsigned w2 = f2bu(b.x) | ((unsigned)f2bu(b.y) << 16);
        unsigned w3 = f2bu(b.z) | ((unsigned)f2bu(b.w) << 16);
        int Wb = (cc >> 1) ^ ((r & 7) << 2);        // granule-4 XOR
        tile32[r][Wb+0] = w0; tile32[r][Wb+1] = w1;
        tile32[r][Wb+2] = w2; tile32[r][Wb+3] = w3;
    }
    __syncthreads();
    {   // phase 2: each thread emits out-row pair (2*r2h, 2*r2h+1), 8 cols
        int r2h = tid >> 3;                 // 0..31  (input word-col)
        int c2  = (tid & 7) * 8;            // input-row chunk / out-col chunk
        unsigned lo[4], hi[4];
#pragma unroll
        for (int j = 0; j < 4; ++j) {
            int R0 = c2 + 2*j, R1 = R0 + 1;
            unsigned wa = tile32[R0][r2h ^ ((R0 & 7) << 2)];
            unsigned wb = tile32[R1][r2h ^ ((R1 & 7) << 2)];
            lo[j] = (wa & 0xFFFFu) | (wb << 16);
            hi[j] = (wa >> 16) | (wb & 0xFFFF0000u);
        }
        __hip_bfloat16* d0 = dst + (size_t)(n0 + 2*r2h)*2048 + k0 + c2;
        *(uint4*)d0          = *(uint4*)lo;
        *(uint4*)(d0 + 2048) = *(uint4*)hi;
    }
}

// ---------------------------------------------------------------------------
// GEMM, A-in-registers / B-in-LDS: C = A[M][K] * BT[N][K]^T.
// MT=4: BM=128 (gemm1-geometry).  MT=2: BM=64 (gemm2-geometry).  BN=128,
// BK=64, 4 waves (2x2; wave-tile MT*16 x 64), 32KB LDS (B double-buffer),
// 2 blocks/CU.  A-fragments global->VGPR, prefetched one BK ahead into aN
// (statically indexed ping-pong; the copy aC=aN is ~32 v_mov, trivial vs
// the ~3450-cyc body).  LDS traffic per CU per BK halves vs the proven R0
// kernel; B swizzle identical.
// ---------------------------------------------------------------------------
template <int MT, typename OT>
__global__ __launch_bounds__(256, 2) void gemm_areg_kernel(
    const __hip_bfloat16* __restrict__ A, const __hip_bfloat16* __restrict__ BT,
    OT* __restrict__ C, int M, int N, int K)
{
    __shared__ __attribute__((aligned(16))) __hip_bfloat16 Bs[2][128*64];  // 2x16KB
    const int tid  = threadIdx.x;
    const int lane = tid & 63;
    const int wave = tid >> 6;
    const int quad = lane >> 4, l15 = lane & 15;
    const int m0 = blockIdx.y * (MT*32), n0 = blockIdx.x * 128;
    const int wm = (wave >> 1) * (MT*16), wn = (wave & 1) * 64;
    const int sw = l15 & 7;                     // row-parity xor term (lane-const)

    f32x4 acc[MT][4] = {};

    // per-lane A base: row (m0+wm+l15), column chunk quad*8
    const __hip_bfloat16* Arow = A + (size_t)(m0 + wm + l15)*K + quad*8;

    auto stageB = [&](int b, int k0) {
#pragma unroll
        for (int p = 0; p < 4; ++p) {           // B: 128 rows x 8 slots of 16B
            int L = p*256 + tid;
            int r = L >> 3, s = L & 7;
            int cs = s ^ (r & 7);
            gld16((char*)&Bs[b][0] + L*16, BT + (size_t)(n0 + r)*K + k0 + cs*8);
        }
    };

    bf16x8 aC[2][MT], aN[2][MT];
#pragma unroll
    for (int ks = 0; ks < 2; ++ks)
#pragma unroll
        for (int t = 0; t < MT; ++t)
            aC[ks][t] = *(const bf16x8*)(Arow + (size_t)t*16*K + ks*32);

    stageB(0, 0);
    const int NTk = K >> 6;
    int cur = 0;
    for (int kt = 0; kt < NTk; ++kt, cur ^= 1) {
        __syncthreads();                        // B[cur] staged; prior aN complete
        const bool hn = (kt + 1 < NTk);
        if (hn) {
            const int nk = (kt + 1) << 6;
            stageB(cur ^ 1, nk);
#pragma unroll
            for (int ks = 0; ks < 2; ++ks)
#pragma unroll
                for (int t = 0; t < MT; ++t)
                    aN[ks][t] = *(const bf16x8*)(Arow + (size_t)t*16*K + nk + ks*32);
        }
#pragma unroll
        for (int ks = 0; ks < 2; ++ks) {        // two 32-k steps within BK=64
            const int slot = ((ks*4 + quad) ^ sw) * 8;
            bf16x8 bfr[4];
#pragma unroll
            for (int t = 0; t < 4; ++t)
                bfr[t] = *(const bf16x8*)(&Bs[cur][0] + (wn + t*16 + l15)*64 + slot);
#pragma unroll
            for (int mt = 0; mt < MT; ++mt)
#pragma unroll
                for (int nt = 0; nt < 4; ++nt)
                    acc[mt][nt] = __builtin_amdgcn_mfma_f32_16x16x32_bf16(aC[ks][mt], bfr[nt], acc[mt][nt], 0, 0, 0);
        }
        if (hn) {
#pragma unroll
            for (int ks = 0; ks < 2; ++ks)
#pragma unroll
                for (int t = 0; t < MT; ++t)
                    aC[ks][t] = aN[ks][t];
        }
    }
#pragma unroll
    for (int mt = 0; mt < MT; ++mt)
#pragma unroll
        for (int nt = 0; nt < 4; ++nt)
#pragma unroll
            for (int r = 0; r < 4; ++r) {
                int row = m0 + wm + mt*16 + quad*4 + r;
                int col = n0 + wn + nt*16 + l15;
                if constexpr (__is_same(OT, float))
                    C[(size_t)row*N + col] = acc[mt][nt][r];
                else
                    C[(size_t)row*N + col] = __float2bfloat16(acc[mt][nt][r]);
            }
}

// ---------------------------------------------------------------------------
// Fused: RMSNorm+RoPE on Q,K rows of QKVraw (blocks 0..2047, one s each)
//        AND V transpose QKVraw -> Vt (blocks 2048..2559, 64x64 tiles,
//        conflict-free u32-pair scheme as in trans_cvt).
// Q output pre-scaled by QK_SCALE*log2(e) (attention uses exp2 directly).
// ---------------------------------------------------------------------------
__global__ __launch_bounds__(256) void rms_vt_kernel(
    const __hip_bfloat16* __restrict__ qkv,
    const float* __restrict__ cosb, const float* __restrict__ sinb,
    const float* __restrict__ qsc,  const float* __restrict__ ksc,
    __hip_bfloat16* __restrict__ Qn, __hip_bfloat16* __restrict__ Kn,
    __hip_bfloat16* __restrict__ Vt)
{
    __shared__ __attribute__((aligned(16))) unsigned tile32[64][37];
    int id = blockIdx.x;
    if (id >= 2048) {   // ---- V transpose tile ----
        int t  = id - 2048;                 // 512 tiles: 32 (s) x 16 (v)
        int s0 = (t & 31) * 64;
        int v0 = (t >> 5) * 64;
        int tid = threadIdx.x;
#pragma unroll
        for (int p = 0; p < 2; ++p) {       // phase 1: swizzled u32 store
            int c = p*256 + tid; int r = c >> 3, cc = (c & 7) * 8;
            uint4 v = *(const uint4*)(qkv + (size_t)(s0 + r)*4096 + 3072 + v0 + cc);
            int Wb = (cc >> 1) ^ ((r & 7) << 2);
            tile32[r][Wb+0] = v.x; tile32[r][Wb+1] = v.y;
            tile32[r][Wb+2] = v.z; tile32[r][Wb+3] = v.w;
        }
        __syncthreads();
        {   // phase 2: out-row pair per thread
            int r2h = tid >> 3;
            int c2  = (tid & 7) * 8;
            unsigned lo[4], hi[4];
#pragma unroll
            for (int j = 0; j < 4; ++j) {
                int R0 = c2 + 2*j, R1 = R0 + 1;
                unsigned wa = tile32[R0][r2h ^ ((R0 & 7) << 2)];
                unsigned wb = tile32[R1][r2h ^ ((R1 & 7) << 2)];
                lo[j] = (wa & 0xFFFFu) | (wb << 16);
                hi[j] = (wa >> 16) | (wb & 0xFFFF0000u);
            }
            __hip_bfloat16* d0 = Vt + (size_t)(v0 + 2*r2h)*2048 + s0 + c2;
            *(uint4*)d0          = *(uint4*)lo;
            *(uint4*)(d0 + 2048) = *(uint4*)hi;
        }
        return;
    }
    // ---- RMSNorm + RoPE ----
    int s = id;
    int wave = threadIdx.x >> 6, lane = threadIdx.x & 63;
    float c1 = cosb[s*128 + lane];
    float c2 = cosb[s*128 + 64 + lane];
    float s1 = sinb[s*128 + lane];
    float s2 = sinb[s*128 + 64 + lane];
    for (int u = wave; u < 24; u += 4) {
        bool isq = (u < 16);
        int h = isq ? u : u - 16;
        const __hip_bfloat16* x = qkv + (size_t)s*4096 + (isq ? h*128 : 2048 + h*128);
        float x1 = (float)x[lane], x2 = (float)x[lane + 64];
        float ss = x1*x1 + x2*x2;
#pragma unroll
        for (int off = 32; off; off >>= 1) ss += __shfl_xor(ss, off);
        float r = rsqrtf(ss * (1.0f/128.0f) + RMS_EPS);
        if (isq) r *= QK_SCALE_L2E;        // fold attn scale + log2e into Q
        const float* sc = isq ? qsc : ksc;
        float y1 = x1 * r * sc[lane];
        float y2 = x2 * r * sc[lane + 64];
        float o1 = y1*c1 - y2*s1;   // d < 64:  x*c - x[d+64]*s
        float o2 = y2*c2 + y1*s2;   // d >= 64: x*c + x[d-64]*s
        __hip_bfloat16* dst = isq ? (Qn + (size_t)s*2048 + h*128)
                                  : (Kn + (size_t)s*1024 + h*128);
        dst[lane]      = __float2bfloat16(o1);
        dst[lane + 64] = __float2bfloat16(o2);
    }
}

// ---------------------------------------------------------------------------
// Flash attention, sliding-window causal — m97-style LDS staging.
//  * Block = 4 waves x 16 q-rows = 64 q-rows of one head; grid 512 (2 blk/CU).
//  * XCD-aware head mapping: XCD x (= bx%8) serves only kv-head x ->
//    its K+V (0.75 MB) stays L2-resident per XCD (T1).
//  * K/V tiles staged into double-buffered LDS via global_load_lds width=16.
//  * XOR-swizzled LDS layouts; one barrier per tile; next staging issued
//    right after it (double buffer overlaps full tile compute).
//  * No online max (scores bounded by RMS-norm); p=exp2(s), per-lane row
//    sums, single cross-lane reduce in epilogue.
// ---------------------------------------------------------------------------
__global__ __launch_bounds__(256, 2) void attn_kernel(
    const __hip_bfloat16* __restrict__ Qn,  // [S][2048], pre-scaled (log2 domain)
    const __hip_bfloat16* __restrict__ Kn,  // [S][1024]
    const __hip_bfloat16* __restrict__ Vt,  // [1024][S]
    __hip_bfloat16* __restrict__ O)         // [S][2048]
{
    __shared__ __attribute__((aligned(16))) __hip_bfloat16 Ksm[2][64*128];  // 2x16KB
    __shared__ __attribute__((aligned(16))) __hip_bfloat16 Vsm[2][128*64];  // 2x16KB
    __shared__ __attribute__((aligned(16))) __hip_bfloat16 P[4][16][76];

    const int bx   = blockIdx.x;
    const int h    = ((bx & 7) << 1) | ((bx >> 3) & 1);   // XCD bx%8 -> kv-head bx%8
    const int qb   = 31 - (bx >> 4);          // long-window blocks dispatched first
    const int i0   = qb * 64;
    const int hk   = h >> 1;
    const int tid  = threadIdx.x, wave = tid >> 6, lane = tid & 63;
    const int quad = lane >> 4, l15 = lane & 15;
    const int ib   = i0 + wave * 16;

    const __hip_bfloat16* Kh = Kn + hk * HDIM;              // row stride 1024
    const __hip_bfloat16* Vh = Vt + (size_t)(hk * HDIM) * 2048;

    // Q fragments (A-operand), fixed for the block
    bf16x8 qf[4];
    const __hip_bfloat16* qbase = Qn + (size_t)(ib + l15)*2048 + h*HDIM + quad*8;
#pragma unroll
    for (int kk = 0; kk < 4; ++kk) qf[kk] = *(const bf16x8*)(qbase + kk*32);

    f32x4 o[8] = {};
    float lrow[4] = {0.f, 0.f, 0.f, 0.f};

    int j_lo = i0 - WIN; if (j_lo < 0) j_lo = 0;
    const int jstart = j_lo & ~63;
    const int jend   = i0;                    // diagonal tile start

    // ---- cooperative staging of one (K,V) tile pair into buffer b ----
    auto stage = [&](int b, int j0) {
#pragma unroll
        for (int p = 0; p < 4; ++p) {         // K: 64 rows x 16 chunks of 16B
            int L = p*256 + tid;
            int r = L >> 4;
            int c = (L & 15) ^ (r & 15);      // XOR swizzle
            gld16((char*)&Ksm[b][0] + L*16, Kh + (size_t)(j0 + r)*1024 + c*8);
        }
#pragma unroll
        for (int p = 0; p < 4; ++p) {         // V: 128 d-rows x 8 chunks of 16B
            int L = p*256 + tid;
            int dv = L >> 3;
            int c = (L & 7) ^ (dv & 7);       // XOR swizzle
            gld16((char*)&Vsm[b][0] + L*16, Vh + (size_t)dv*2048 + j0 + c*8);
        }
    };

    stage(0, jstart);
    int cur = 0;
    for (int j0 = jstart; j0 <= jend; j0 += 64, cur ^= 1) {
        __syncthreads();                      // drains staging vmcnt + syncs buffers
        if (j0 + 64 <= jend) stage(cur ^ 1, j0 + 64);

        // ---- S = Q K^T (16 x 64 per wave), frags from swizzled LDS ----
        f32x4 sacc[4] = {};
#pragma unroll
        for (int nt = 0; nt < 4; ++nt) {
            const int r = nt*16 + l15;
#pragma unroll
            for (int kk = 0; kk < 4; ++kk) {
                const int cc = (kk*4 + quad) ^ l15;   // swizzled chunk
                bf16x8 kfr = *(const bf16x8*)(&Ksm[cur][0] + r*128 + cc*8);
                sacc[nt] = __builtin_amdgcn_mfma_f32_16x16x32_bf16(qf[kk], kfr, sacc[nt], 0, 0, 0);
            }
        }

        // ---- p = exp2(s), P write, per-lane row-sum ----
        const bool need_mask = (j0 + 63 > ib) || (j0 < ib + 15 - WIN);
        if (need_mask) {
#pragma unroll
            for (int nt = 0; nt < 4; ++nt) {
                int j = j0 + nt*16 + l15;
#pragma unroll
                for (int r = 0; r < 4; ++r) {
                    int i = ib + quad*4 + r;
                    bool valid = (j <= i) && (i - j <= WIN);
                    float p = valid ? __builtin_exp2f(sacc[nt][r]) : 0.f;
                    lrow[r] += p;
                    P[wave][quad*4 + r][nt*16 + l15] = __float2bfloat16(p);
                }
            }
        } else {
#pragma unroll
            for (int nt = 0; nt < 4; ++nt)
#pragma unroll
                for (int r = 0; r < 4; ++r) {
                    float p = __builtin_exp2f(sacc[nt][r]);
                    lrow[r] += p;
                    P[wave][quad*4 + r][nt*16 + l15] = __float2bfloat16(p);
                }
        }

        // ---- O += P V (P per-wave, lgkm-ordered; V frags from swizzled LDS) ----
#pragma unroll
        for (int ks = 0; ks < 2; ++ks) {
            bf16x8 pf = *(const bf16x8*)&P[wave][l15][ks*32 + quad*8];
#pragma unroll
            for (int dt = 0; dt < 8; ++dt) {
                const int dv = dt*16 + l15;
                const int cc = (ks*4 + quad) ^ (l15 & 7);
                bf16x8 vfr = *(const bf16x8*)(&Vsm[cur][0] + dv*64 + cc*8);
                o[dt] = __builtin_amdgcn_mfma_f32_16x16x32_bf16(pf, vfr, o[dt], 0, 0, 0);
            }
        }
    }

    // ---- epilogue: single cross-lane reduce of lrow, normalize, store ----
#pragma unroll
    for (int r = 0; r < 4; ++r) {
        lrow[r] += __shfl_xor(lrow[r], 1);
        lrow[r] += __shfl_xor(lrow[r], 2);
        lrow[r] += __shfl_xor(lrow[r], 4);
        lrow[r] += __shfl_xor(lrow[r], 8);
        float inv = 1.0f / lrow[r];
        int row = ib + quad*4 + r;
#pragma unroll
        for (int dt = 0; dt < 8; ++dt)
            O[(size_t)row*2048 + h*HDIM + dt*16 + l15] = __float2bfloat16(o[dt][r] * inv);
    }
}

// ---------------------------------------------------------------------------
extern "C" void kernel_launch(void* const* d_in, const int* in_sizes, int n_in,
                              void* d_out, int out_size, void* d_ws, size_t ws_size,
                              hipStream_t stream)
{
    (void)in_sizes; (void)n_in; (void)out_size; (void)ws_size;
    const float* hs   = (const float*)d_in[0];
    const float* cosb = (const float*)d_in[1];
    const float* sinb = (const float*)d_in[2];
    const float* Wq   = (const float*)d_in[3];
    const float* Wk   = (const float*)d_in[4];
    const float* Wv   = (const float*)d_in[5];
    const float* Wo   = (const float*)d_in[6];
    const float* qs   = (const float*)d_in[7];
    const float* ks   = (const float*)d_in[8];

    char* ws = (char*)d_ws;
    __hip_bfloat16* WqkvT = (__hip_bfloat16*)(ws);
    __hip_bfloat16* WoT   = (__hip_bfloat16*)(ws + (16u << 20));
    __hip_bfloat16* QKV   = (__hip_bfloat16*)(ws + (24u << 20));
    __hip_bfloat16* Qn    = (__hip_bfloat16*)(ws + (40u << 20));
    __hip_bfloat16* Kn    = (__hip_bfloat16*)(ws + (48u << 20));
    __hip_bfloat16* Vt    = (__hip_bfloat16*)(ws + (52u << 20));
    __hip_bfloat16* hsb   = (__hip_bfloat16*)(ws + (56u << 20)); // overlaid with AT
    __hip_bfloat16* AT    = (__hip_bfloat16*)(ws + (56u << 20)); // disjoint liveness

    trans_cvt_kernel<<<dim3(5120), dim3(256), 0, stream>>>(Wq, Wk, Wv, Wo, hs, WqkvT, WoT, hsb);
    gemm_areg_kernel<4, __hip_bfloat16><<<dim3(32, 16), dim3(256), 0, stream>>>(hsb, WqkvT, QKV, 2048, 4096, 2048);
    rms_vt_kernel<<<dim3(2560), dim3(256), 0, stream>>>(QKV, cosb, sinb, qs, ks, Qn, Kn, Vt);
    attn_kernel<<<dim3(512), dim3(256), 0, stream>>>(Qn, Kn, Vt, AT);
    gemm_areg_kernel<2, float><<<dim3(16, 32), dim3(256), 0, stream>>>(AT, WoT, (float*)d_out, 2048, 2048, 2048);
}

// Round 8
// 257.448 us; speedup vs baseline: 1.0337x; 1.0337x over previous
//
#include <hip/hip_runtime.h>
#include <hip/hip_bf16.h>
#include <cmath>

// I/O: all inputs float32 (per reference setup_inputs), output float32.
// Internal compute: bf16 MFMA with fp32 accumulation.
//
// Workspace layout (64 MB total):
//  [0,16M)   WqkvT  [4096][2048] bf16   (rows: 0-2047 WqT, 2048-3071 WkT, 3072-4095 WvT)
//  [16,24M)  WoT    [2048][2048] bf16
//  [24,40M)  QKVraw [2048][4096] bf16
//  [40,48M)  Qn     [2048][2048] bf16   (post rms+rope, pre-scaled by QK_SCALE*log2e)
//  [48,52M)  Kn     [2048][1024] bf16
//  [52,56M)  Vt     [1024][2048] bf16   ([hkv*128 d][s])
//  [56,64M)  hsb    [2048][2048] bf16   (live: kernels 1-2)   }  overlaid,
//  [56,64M)  AT     [2048][2048] bf16   (live: kernels 4-5)   }  disjoint liveness
//
// R8: GEMMs reverted to the proven R5 kernels (A-in-reg falsified in R7:
// 16-row-scatter loads + vmcnt drain = latency-bound 76us).  One change:
// attn drops V staging entirely (catalog m169: LDS-staging L2-fit data is
// pure overhead) -- V-fragments are read direct from Vt, which is
// XCD-L2-resident under the R5 head mapping; the 16 loads issue right
// after QK^T and hide under the exp2/P-write section.  Removes per
// block-iter: 16KB V gld_lds + 64KB Vsm ds_read (~45% of attn LDS traffic).

typedef __bf16 bf16x8 __attribute__((ext_vector_type(8)));
typedef float  f32x4  __attribute__((ext_vector_type(4)));

#define S_LEN    2048
#define NH       16
#define NKV      8
#define HDIM     128
#define WIN      1024
// QK_SCALE * log2(e): scores computed directly in log2 domain -> exp2
#define QK_SCALE_L2E 0.12751744595f
#define RMS_EPS  1e-6f

__device__ __forceinline__ void gld16(void* lds, const void* g) {
    __builtin_amdgcn_global_load_lds(
        (const __attribute__((address_space(1))) unsigned int*)g,
        (__attribute__((address_space(3))) unsigned int*)lds, 16, 0, 0);
}

__device__ __forceinline__ unsigned short f2bu(float x) {
    __hip_bfloat16 h = __float2bfloat16(x);
    return *(unsigned short*)&h;
}

// ---------------------------------------------------------------------------
// Fused: weight transpose + f32->bf16 (blocks 0..3071)  AND
//        hidden_states f32->bf16 convert (blocks 3072..5119).
// Conflict-free u32-pair transpose tile (see R5 notes).
// ---------------------------------------------------------------------------
__global__ __launch_bounds__(256) void trans_cvt_kernel(
    const float* __restrict__ Wq, const float* __restrict__ Wk,
    const float* __restrict__ Wv, const float* __restrict__ Wo,
    const float* __restrict__ hs,
    __hip_bfloat16* __restrict__ WqkvT, __hip_bfloat16* __restrict__ WoT,
    __hip_bfloat16* __restrict__ hsb)
{
    __shared__ __attribute__((aligned(16))) unsigned tile32[64][37];
    int id = blockIdx.x;
    if (id >= 3072) {   // ---- hidden_states convert: 8 elems/thread ----
        size_t i = ((size_t)(id - 3072) * 256 + threadIdx.x) * 8;
        float4 a = *(const float4*)(hs + i);
        float4 b = *(const float4*)(hs + i + 4);
        unsigned short u[8] = { f2bu(a.x), f2bu(a.y), f2bu(a.z), f2bu(a.w),
                                f2bu(b.x), f2bu(b.y), f2bu(b.z), f2bu(b.w) };
        *(uint4*)(hsb + i) = *(uint4*)u;
        return;
    }
    const float* src; __hip_bfloat16* dst; int N, kt, nt;
    if (id < 1024)      { src = Wq; dst = WqkvT;                          N = 2048; kt = id >> 5;          nt = id & 31; }
    else if (id < 1536) { src = Wk; dst = WqkvT + (size_t)2048*2048;      N = 1024; kt = (id-1024) >> 4;   nt = (id-1024) & 15; }
    else if (id < 2048) { src = Wv; dst = WqkvT + (size_t)3072*2048;      N = 1024; kt = (id-1536) >> 4;   nt = (id-1536) & 15; }
    else                { src = Wo; dst = WoT;                            N = 2048; kt = (id-2048) >> 5;   nt = (id-2048) & 31; }
    int k0 = kt * 64, n0 = nt * 64;
    int tid = threadIdx.x;
#pragma unroll
    for (int p = 0; p < 2; ++p) {           // phase 1: read rows, cvt, swizzled store
        int c = p*256 + tid; int r = c >> 3, cc = (c & 7) * 8;
        const float* s = src + (size_t)(k0 + r)*N + n0 + cc;
        float4 a = *(const float4*)s;
        float4 b = *(const float4*)(s + 4);
        unsigned w0 = f2bu(a.x) | ((unsigned)f2bu(a.y) << 16);
        unsigned w1 = f2bu(a.z) | ((unsigned)f2bu(a.w) << 16);
        unsigned w2 = f2bu(b.x) | ((unsigned)f2bu(b.y) << 16);
        unsigned w3 = f2bu(b.z) | ((unsigned)f2bu(b.w) << 16);
        int Wb = (cc >> 1) ^ ((r & 7) << 2);        // granule-4 XOR
        tile32[r][Wb+0] = w0; tile32[r][Wb+1] = w1;
        tile32[r][Wb+2] = w2; tile32[r][Wb+3] = w3;
    }
    __syncthreads();
    {   // phase 2: each thread emits out-row pair (2*r2h, 2*r2h+1), 8 cols
        int r2h = tid >> 3;                 // 0..31  (input word-col)
        int c2  = (tid & 7) * 8;            // input-row chunk / out-col chunk
        unsigned lo[4], hi[4];
#pragma unroll
        for (int j = 0; j < 4; ++j) {
            int R0 = c2 + 2*j, R1 = R0 + 1;
            unsigned wa = tile32[R0][r2h ^ ((R0 & 7) << 2)];
            unsigned wb = tile32[R1][r2h ^ ((R1 & 7) << 2)];
            lo[j] = (wa & 0xFFFFu) | (wb << 16);
            hi[j] = (wa >> 16) | (wb & 0xFFFF0000u);
        }
        __hip_bfloat16* d0 = dst + (size_t)(n0 + 2*r2h)*2048 + k0 + c2;
        *(uint4*)d0          = *(uint4*)lo;
        *(uint4*)(d0 + 2048) = *(uint4*)hi;
    }
}

// ---------------------------------------------------------------------------
// GEMM: C[M][N] = A[M][K] * BT[N][K]^T.
// BM=128 x BN=128, BK=64, double-buffered LDS (64 KB), 4 waves (2x2,
// wave-tile 64x64), 2 blocks/CU.  The proven 42-48us/~800TF structure.
// ---------------------------------------------------------------------------
template <typename OT>
__global__ __launch_bounds__(256, 2) void gemm_bt_kernel(
    const __hip_bfloat16* __restrict__ A, const __hip_bfloat16* __restrict__ BT,
    OT* __restrict__ C, int M, int N, int K)
{
    __shared__ __attribute__((aligned(16))) __hip_bfloat16 As[2][128*64];  // 2x16KB
    __shared__ __attribute__((aligned(16))) __hip_bfloat16 Bs[2][128*64];  // 2x16KB
    const int tid  = threadIdx.x;
    const int lane = tid & 63;
    const int wave = tid >> 6;
    const int quad = lane >> 4, l15 = lane & 15;
    const int m0 = blockIdx.y * 128, n0 = blockIdx.x * 128;
    const int wm = (wave >> 1) * 64, wn = (wave & 1) * 64;
    const int sw = l15 & 7;                     // row-parity xor term (lane-const)

    f32x4 acc[4][4] = {};

    auto stage = [&](int b, int k0) {
#pragma unroll
        for (int p = 0; p < 4; ++p) {           // A: 128 rows x 8 slots of 16B
            int L = p*256 + tid;
            int r = L >> 3, s = L & 7;
            int cs = s ^ (r & 7);
            gld16((char*)&As[b][0] + L*16, A + (size_t)(m0 + r)*K + k0 + cs*8);
        }
#pragma unroll
        for (int p = 0; p < 4; ++p) {           // B: 128 rows x 8 slots of 16B
            int L = p*256 + tid;
            int r = L >> 3, s = L & 7;
            int cs = s ^ (r & 7);
            gld16((char*)&Bs[b][0] + L*16, BT + (size_t)(n0 + r)*K + k0 + cs*8);
        }
    };

    const int NT = K >> 6;
    stage(0, 0);
    int cur = 0;
    for (int kt = 0; kt < NT; ++kt, cur ^= 1) {
        __syncthreads();                        // staging for cur done; waves synced
        if (kt + 1 < NT) stage(cur ^ 1, (kt + 1) << 6);
#pragma unroll
        for (int ks = 0; ks < 2; ++ks) {        // two 32-k steps within BK=64
            const int slot = ((ks*4 + quad) ^ sw) * 8;
            bf16x8 af[4], bfr[4];
#pragma unroll
            for (int t = 0; t < 4; ++t) {
                af[t]  = *(const bf16x8*)(&As[cur][0] + (wm + t*16 + l15)*64 + slot);
                bfr[t] = *(const bf16x8*)(&Bs[cur][0] + (wn + t*16 + l15)*64 + slot);
            }
#pragma unroll
            for (int mt = 0; mt < 4; ++mt)
#pragma unroll
                for (int nt = 0; nt < 4; ++nt)
                    acc[mt][nt] = __builtin_amdgcn_mfma_f32_16x16x32_bf16(af[mt], bfr[nt], acc[mt][nt], 0, 0, 0);
        }
    }
#pragma unroll
    for (int mt = 0; mt < 4; ++mt)
#pragma unroll
        for (int nt = 0; nt < 4; ++nt)
#pragma unroll
            for (int r = 0; r < 4; ++r) {
                int row = m0 + wm + mt*16 + quad*4 + r;
                int col = n0 + wn + nt*16 + l15;
                if constexpr (__is_same(OT, float))
                    C[(size_t)row*N + col] = acc[mt][nt][r];
                else
                    C[(size_t)row*N + col] = __float2bfloat16(acc[mt][nt][r]);
            }
}

// ---------------------------------------------------------------------------
// GEMM, 64x128 tile (output projection, M=N=2048): BM=64 x BN=128, BK=64,
// 48 KB LDS, 4 waves (2x2, wave-tile 32x64), grid 512 blocks = 2 blk/CU.
// ---------------------------------------------------------------------------
template <typename OT>
__global__ __launch_bounds__(256, 2) void gemm_bt64_kernel(
    const __hip_bfloat16* __restrict__ A, const __hip_bfloat16* __restrict__ BT,
    OT* __restrict__ C, int M, int N, int K)
{
    __shared__ __attribute__((aligned(16))) __hip_bfloat16 As[2][64*64];   // 2x8KB
    __shared__ __attribute__((aligned(16))) __hip_bfloat16 Bs[2][128*64];  // 2x16KB
    const int tid  = threadIdx.x;
    const int lane = tid & 63;
    const int wave = tid >> 6;
    const int quad = lane >> 4, l15 = lane & 15;
    const int m0 = blockIdx.y * 64, n0 = blockIdx.x * 128;
    const int wm = (wave >> 1) * 32, wn = (wave & 1) * 64;
    const int sw = l15 & 7;                     // row-parity xor term (lane-const)

    f32x4 acc[2][4] = {};

    auto stage = [&](int b, int k0) {
#pragma unroll
        for (int p = 0; p < 2; ++p) {           // A: 64 rows x 8 slots of 16B
            int L = p*256 + tid;
            int r = L >> 3, s = L & 7;
            int cs = s ^ (r & 7);
            gld16((char*)&As[b][0] + L*16, A + (size_t)(m0 + r)*K + k0 + cs*8);
        }
#pragma unroll
        for (int p = 0; p < 4; ++p) {           // B: 128 rows x 8 slots of 16B
            int L = p*256 + tid;
            int r = L >> 3, s = L & 7;
            int cs = s ^ (r & 7);
            gld16((char*)&Bs[b][0] + L*16, BT + (size_t)(n0 + r)*K + k0 + cs*8);
        }
    };

    const int NT = K >> 6;
    stage(0, 0);
    int cur = 0;
    for (int kt = 0; kt < NT; ++kt, cur ^= 1) {
        __syncthreads();                        // staging for cur done; waves synced
        if (kt + 1 < NT) stage(cur ^ 1, (kt + 1) << 6);
#pragma unroll
        for (int ks = 0; ks < 2; ++ks) {        // two 32-k steps within BK=64
            const int slot = ((ks*4 + quad) ^ sw) * 8;
            bf16x8 af[2], bfr[4];
#pragma unroll
            for (int t = 0; t < 2; ++t)
                af[t]  = *(const bf16x8*)(&As[cur][0] + (wm + t*16 + l15)*64 + slot);
#pragma unroll
            for (int t = 0; t < 4; ++t)
                bfr[t] = *(const bf16x8*)(&Bs[cur][0] + (wn + t*16 + l15)*64 + slot);
#pragma unroll
            for (int mt = 0; mt < 2; ++mt)
#pragma unroll
                for (int nt = 0; nt < 4; ++nt)
                    acc[mt][nt] = __builtin_amdgcn_mfma_f32_16x16x32_bf16(af[mt], bfr[nt], acc[mt][nt], 0, 0, 0);
        }
    }
#pragma unroll
    for (int mt = 0; mt < 2; ++mt)
#pragma unroll
        for (int nt = 0; nt < 4; ++nt)
#pragma unroll
            for (int r = 0; r < 4; ++r) {
                int row = m0 + wm + mt*16 + quad*4 + r;
                int col = n0 + wn + nt*16 + l15;
                if constexpr (__is_same(OT, float))
                    C[(size_t)row*N + col] = acc[mt][nt][r];
                else
                    C[(size_t)row*N + col] = __float2bfloat16(acc[mt][nt][r]);
            }
}

// ---------------------------------------------------------------------------
// Fused: RMSNorm+RoPE on Q,K rows of QKVraw (blocks 0..2047, one s each)
//        AND V transpose QKVraw -> Vt (blocks 2048..2559, 64x64 tiles,
//        conflict-free u32-pair scheme as in trans_cvt).
// Q output pre-scaled by QK_SCALE*log2(e) (attention uses exp2 directly).
// ---------------------------------------------------------------------------
__global__ __launch_bounds__(256) void rms_vt_kernel(
    const __hip_bfloat16* __restrict__ qkv,
    const float* __restrict__ cosb, const float* __restrict__ sinb,
    const float* __restrict__ qsc,  const float* __restrict__ ksc,
    __hip_bfloat16* __restrict__ Qn, __hip_bfloat16* __restrict__ Kn,
    __hip_bfloat16* __restrict__ Vt)
{
    __shared__ __attribute__((aligned(16))) unsigned tile32[64][37];
    int id = blockIdx.x;
    if (id >= 2048) {   // ---- V transpose tile ----
        int t  = id - 2048;                 // 512 tiles: 32 (s) x 16 (v)
        int s0 = (t & 31) * 64;
        int v0 = (t >> 5) * 64;
        int tid = threadIdx.x;
#pragma unroll
        for (int p = 0; p < 2; ++p) {       // phase 1: swizzled u32 store
            int c = p*256 + tid; int r = c >> 3, cc = (c & 7) * 8;
            uint4 v = *(const uint4*)(qkv + (size_t)(s0 + r)*4096 + 3072 + v0 + cc);
            int Wb = (cc >> 1) ^ ((r & 7) << 2);
            tile32[r][Wb+0] = v.x; tile32[r][Wb+1] = v.y;
            tile32[r][Wb+2] = v.z; tile32[r][Wb+3] = v.w;
        }
        __syncthreads();
        {   // phase 2: out-row pair per thread
            int r2h = tid >> 3;
            int c2  = (tid & 7) * 8;
            unsigned lo[4], hi[4];
#pragma unroll
            for (int j = 0; j < 4; ++j) {
                int R0 = c2 + 2*j, R1 = R0 + 1;
                unsigned wa = tile32[R0][r2h ^ ((R0 & 7) << 2)];
                unsigned wb = tile32[R1][r2h ^ ((R1 & 7) << 2)];
                lo[j] = (wa & 0xFFFFu) | (wb << 16);
                hi[j] = (wa >> 16) | (wb & 0xFFFF0000u);
            }
            __hip_bfloat16* d0 = Vt + (size_t)(v0 + 2*r2h)*2048 + s0 + c2;
            *(uint4*)d0          = *(uint4*)lo;
            *(uint4*)(d0 + 2048) = *(uint4*)hi;
        }
        return;
    }
    // ---- RMSNorm + RoPE ----
    int s = id;
    int wave = threadIdx.x >> 6, lane = threadIdx.x & 63;
    float c1 = cosb[s*128 + lane];
    float c2 = cosb[s*128 + 64 + lane];
    float s1 = sinb[s*128 + lane];
    float s2 = sinb[s*128 + 64 + lane];
    for (int u = wave; u < 24; u += 4) {
        bool isq = (u < 16);
        int h = isq ? u : u - 16;
        const __hip_bfloat16* x = qkv + (size_t)s*4096 + (isq ? h*128 : 2048 + h*128);
        float x1 = (float)x[lane], x2 = (float)x[lane + 64];
        float ss = x1*x1 + x2*x2;
#pragma unroll
        for (int off = 32; off; off >>= 1) ss += __shfl_xor(ss, off);
        float r = rsqrtf(ss * (1.0f/128.0f) + RMS_EPS);
        if (isq) r *= QK_SCALE_L2E;        // fold attn scale + log2e into Q
        const float* sc = isq ? qsc : ksc;
        float y1 = x1 * r * sc[lane];
        float y2 = x2 * r * sc[lane + 64];
        float o1 = y1*c1 - y2*s1;   // d < 64:  x*c - x[d+64]*s
        float o2 = y2*c2 + y1*s2;   // d >= 64: x*c + x[d-64]*s
        __hip_bfloat16* dst = isq ? (Qn + (size_t)s*2048 + h*128)
                                  : (Kn + (size_t)s*1024 + h*128);
        dst[lane]      = __float2bfloat16(o1);
        dst[lane + 64] = __float2bfloat16(o2);
    }
}

// ---------------------------------------------------------------------------
// Flash attention, sliding-window causal.
//  * Block = 4 waves x 16 q-rows = 64 q-rows of one head; grid 512 (2 blk/CU).
//  * XCD-aware head mapping: XCD x (= bx%8) serves only kv-head x ->
//    its K+V (0.75 MB) stays L2-resident per XCD (T1).
//  * K tiles staged into double-buffered LDS via global_load_lds width=16.
//  * V read DIRECT from global (XCD-L2-resident; m169: staging L2-fit data
//    is pure overhead).  16 loads issued right after QK^T, hidden under the
//    exp2/P-write section.
//  * No online max (scores bounded by RMS-norm); p=exp2(s), per-lane row
//    sums, single cross-lane reduce in epilogue.
// ---------------------------------------------------------------------------
__global__ __launch_bounds__(256, 2) void attn_kernel(
    const __hip_bfloat16* __restrict__ Qn,  // [S][2048], pre-scaled (log2 domain)
    const __hip_bfloat16* __restrict__ Kn,  // [S][1024]
    const __hip_bfloat16* __restrict__ Vt,  // [1024][S]
    __hip_bfloat16* __restrict__ O)         // [S][2048]
{
    __shared__ __attribute__((aligned(16))) __hip_bfloat16 Ksm[2][64*128];  // 2x16KB
    __shared__ __attribute__((aligned(16))) __hip_bfloat16 P[4][16][76];

    const int bx   = blockIdx.x;
    const int h    = ((bx & 7) << 1) | ((bx >> 3) & 1);   // XCD bx%8 -> kv-head bx%8
    const int qb   = 31 - (bx >> 4);          // long-window blocks dispatched first
    const int i0   = qb * 64;
    const int hk   = h >> 1;
    const int tid  = threadIdx.x, wave = tid >> 6, lane = tid & 63;
    const int quad = lane >> 4, l15 = lane & 15;
    const int ib   = i0 + wave * 16;

    const __hip_bfloat16* Kh = Kn + hk * HDIM;              // row stride 1024
    const __hip_bfloat16* Vh = Vt + (size_t)(hk * HDIM) * 2048;
    // per-lane V base: d-row (l15), column chunk quad*8 (advanced by j0, dt, ks)
    const __hip_bfloat16* Vl = Vh + (size_t)l15*2048 + quad*8;

    // Q fragments (A-operand), fixed for the block
    bf16x8 qf[4];
    const __hip_bfloat16* qbase = Qn + (size_t)(ib + l15)*2048 + h*HDIM + quad*8;
#pragma unroll
    for (int kk = 0; kk < 4; ++kk) qf[kk] = *(const bf16x8*)(qbase + kk*32);

    f32x4 o[8] = {};
    float lrow[4] = {0.f, 0.f, 0.f, 0.f};

    int j_lo = i0 - WIN; if (j_lo < 0) j_lo = 0;
    const int jstart = j_lo & ~63;
    const int jend   = i0;                    // diagonal tile start

    // ---- cooperative staging of one K tile into buffer b ----
    auto stage = [&](int b, int j0) {
#pragma unroll
        for (int p = 0; p < 4; ++p) {         // K: 64 rows x 16 chunks of 16B
            int L = p*256 + tid;
            int r = L >> 4;
            int c = (L & 15) ^ (r & 15);      // XOR swizzle
            gld16((char*)&Ksm[b][0] + L*16, Kh + (size_t)(j0 + r)*1024 + c*8);
        }
    };

    stage(0, jstart);
    int cur = 0;
    for (int j0 = jstart; j0 <= jend; j0 += 64, cur ^= 1) {
        __syncthreads();                      // drains staging vmcnt + syncs buffers
        if (j0 + 64 <= jend) stage(cur ^ 1, j0 + 64);

        // ---- S = Q K^T (16 x 64 per wave), frags from swizzled LDS ----
        f32x4 sacc[4] = {};
#pragma unroll
        for (int nt = 0; nt < 4; ++nt) {
            const int r = nt*16 + l15;
#pragma unroll
            for (int kk = 0; kk < 4; ++kk) {
                const int cc = (kk*4 + quad) ^ l15;   // swizzled chunk
                bf16x8 kfr = *(const bf16x8*)(&Ksm[cur][0] + r*128 + cc*8);
                sacc[nt] = __builtin_amdgcn_mfma_f32_16x16x32_bf16(qf[kk], kfr, sacc[nt], 0, 0, 0);
            }
        }

        // ---- V fragments direct from global (L2-resident), issued early ----
        bf16x8 vf0[8], vf1[8];
#pragma unroll
        for (int dt = 0; dt < 8; ++dt) {
            const __hip_bfloat16* vb = Vl + (size_t)dt*16*2048 + j0;
            vf0[dt] = *(const bf16x8*)(vb);
            vf1[dt] = *(const bf16x8*)(vb + 32);
        }

        // ---- p = exp2(s), P write, per-lane row-sum ----
        const bool need_mask = (j0 + 63 > ib) || (j0 < ib + 15 - WIN);
        if (need_mask) {
#pragma unroll
            for (int nt = 0; nt < 4; ++nt) {
                int j = j0 + nt*16 + l15;
#pragma unroll
                for (int r = 0; r < 4; ++r) {
                    int i = ib + quad*4 + r;
                    bool valid = (j <= i) && (i - j <= WIN);
                    float p = valid ? __builtin_exp2f(sacc[nt][r]) : 0.f;
                    lrow[r] += p;
                    P[wave][quad*4 + r][nt*16 + l15] = __float2bfloat16(p);
                }
            }
        } else {
#pragma unroll
            for (int nt = 0; nt < 4; ++nt)
#pragma unroll
                for (int r = 0; r < 4; ++r) {
                    float p = __builtin_exp2f(sacc[nt][r]);
                    lrow[r] += p;
                    P[wave][quad*4 + r][nt*16 + l15] = __float2bfloat16(p);
                }
        }

        // ---- O += P V (P per-wave, lgkm-ordered; V frags in registers) ----
#pragma unroll
        for (int ks = 0; ks < 2; ++ks) {
            bf16x8 pf = *(const bf16x8*)&P[wave][l15][ks*32 + quad*8];
#pragma unroll
            for (int dt = 0; dt < 8; ++dt)
                o[dt] = __builtin_amdgcn_mfma_f32_16x16x32_bf16(
                            pf, ks ? vf1[dt] : vf0[dt], o[dt], 0, 0, 0);
        }
    }

    // ---- epilogue: single cross-lane reduce of lrow, normalize, store ----
#pragma unroll
    for (int r = 0; r < 4; ++r) {
        lrow[r] += __shfl_xor(lrow[r], 1);
        lrow[r] += __shfl_xor(lrow[r], 2);
        lrow[r] += __shfl_xor(lrow[r], 4);
        lrow[r] += __shfl_xor(lrow[r], 8);
        float inv = 1.0f / lrow[r];
        int row = ib + quad*4 + r;
#pragma unroll
        for (int dt = 0; dt < 8; ++dt)
            O[(size_t)row*2048 + h*HDIM + dt*16 + l15] = __float2bfloat16(o[dt][r] * inv);
    }
}

// ---------------------------------------------------------------------------
extern "C" void kernel_launch(void* const* d_in, const int* in_sizes, int n_in,
                              void* d_out, int out_size, void* d_ws, size_t ws_size,
                              hipStream_t stream)
{
    (void)in_sizes; (void)n_in; (void)out_size; (void)ws_size;
    const float* hs   = (const float*)d_in[0];
    const float* cosb = (const float*)d_in[1];
    const float* sinb = (const float*)d_in[2];
    const float* Wq   = (const float*)d_in[3];
    const float* Wk   = (const float*)d_in[4];
    const float* Wv   = (const float*)d_in[5];
    const float* Wo   = (const float*)d_in[6];
    const float* qs   = (const float*)d_in[7];
    const float* ks   = (const float*)d_in[8];

    char* ws = (char*)d_ws;
    __hip_bfloat16* WqkvT = (__hip_bfloat16*)(ws);
    __hip_bfloat16* WoT   = (__hip_bfloat16*)(ws + (16u << 20));
    __hip_bfloat16* QKV   = (__hip_bfloat16*)(ws + (24u << 20));
    __hip_bfloat16* Qn    = (__hip_bfloat16*)(ws + (40u << 20));
    __hip_bfloat16* Kn    = (__hip_bfloat16*)(ws + (48u << 20));
    __hip_bfloat16* Vt    = (__hip_bfloat16*)(ws + (52u << 20));
    __hip_bfloat16* hsb   = (__hip_bfloat16*)(ws + (56u << 20)); // overlaid with AT
    __hip_bfloat16* AT    = (__hip_bfloat16*)(ws + (56u << 20)); // disjoint liveness

    trans_cvt_kernel<<<dim3(5120), dim3(256), 0, stream>>>(Wq, Wk, Wv, Wo, hs, WqkvT, WoT, hsb);
    gemm_bt_kernel<__hip_bfloat16><<<dim3(32, 16), dim3(256), 0, stream>>>(hsb, WqkvT, QKV, 2048, 4096, 2048);
    rms_vt_kernel<<<dim3(2560), dim3(256), 0, stream>>>(QKV, cosb, sinb, qs, ks, Qn, Kn, Vt);
    attn_kernel<<<dim3(512), dim3(256), 0, stream>>>(Qn, Kn, Vt, AT);
    gemm_bt64_kernel<float><<<dim3(16, 32), dim3(256), 0, stream>>>(AT, WoT, (float*)d_out, 2048, 2048, 2048);
}

// Round 9
// 220.547 us; speedup vs baseline: 1.2067x; 1.1673x over previous
//
#include <hip/hip_runtime.h>
#include <hip/hip_bf16.h>
#include <cmath>

// I/O: all inputs float32 (per reference setup_inputs), output float32.
// Internal compute: bf16 MFMA with fp32 accumulation.
//
// Workspace layout (64 MB total):
//  [0,16M)   WqkvT  [4096][2048] bf16   (rows: 0-2047 WqT, 2048-3071 WkT, 3072-4095 WvT)
//  [16,24M)  WoT    [2048][2048] bf16
//  [24,40M)  QKVraw [2048][4096] bf16
//  [40,48M)  Qn     [2048][2048] bf16   (post rms+rope, pre-scaled by QK_SCALE*log2e)
//  [48,52M)  Kn     [2048][1024] bf16
//  [52,56M)  Vt     [1024][2048] bf16   ([hkv*128 d][s])
//  [56,64M)  hsb    [2048][2048] bf16   (live: kernels 1-2)   }  overlaid,
//  [56,64M)  AT     [2048][2048] bf16   (live: kernels 4-5)   }  disjoint liveness
//
// R9 = R5 (best known, 218.7us) + T5 setprio around attn MFMA clusters.
// R7/R8 lesson (recorded): per-lane row-strided global fragment loads are
// 16-line gathers -> latency-bound collapse; MFMA operands must be staged
// via gld_lds + swizzled LDS.  GEMMs at their proven local optimum.
// attn is barrier/latency-bound with 2 heterogeneous blocks/CU -> the one
// catalog lever measured positive in exactly this regime is s_setprio
// (m191 attn +4-7%; m190 GEMM-lockstep null -- so GEMMs left untouched).

typedef __bf16 bf16x8 __attribute__((ext_vector_type(8)));
typedef float  f32x4  __attribute__((ext_vector_type(4)));

#define S_LEN    2048
#define NH       16
#define NKV      8
#define HDIM     128
#define WIN      1024
// QK_SCALE * log2(e): scores computed directly in log2 domain -> exp2
#define QK_SCALE_L2E 0.12751744595f
#define RMS_EPS  1e-6f

__device__ __forceinline__ void gld16(void* lds, const void* g) {
    __builtin_amdgcn_global_load_lds(
        (const __attribute__((address_space(1))) unsigned int*)g,
        (__attribute__((address_space(3))) unsigned int*)lds, 16, 0, 0);
}

__device__ __forceinline__ unsigned short f2bu(float x) {
    __hip_bfloat16 h = __float2bfloat16(x);
    return *(unsigned short*)&h;
}

// ---------------------------------------------------------------------------
// Fused: weight transpose + f32->bf16 (blocks 0..3071)  AND
//        hidden_states f32->bf16 convert (blocks 3072..5119).
// Conflict-free u32-pair transpose tile (see R5 notes).
// ---------------------------------------------------------------------------
__global__ __launch_bounds__(256) void trans_cvt_kernel(
    const float* __restrict__ Wq, const float* __restrict__ Wk,
    const float* __restrict__ Wv, const float* __restrict__ Wo,
    const float* __restrict__ hs,
    __hip_bfloat16* __restrict__ WqkvT, __hip_bfloat16* __restrict__ WoT,
    __hip_bfloat16* __restrict__ hsb)
{
    __shared__ __attribute__((aligned(16))) unsigned tile32[64][37];
    int id = blockIdx.x;
    if (id >= 3072) {   // ---- hidden_states convert: 8 elems/thread ----
        size_t i = ((size_t)(id - 3072) * 256 + threadIdx.x) * 8;
        float4 a = *(const float4*)(hs + i);
        float4 b = *(const float4*)(hs + i + 4);
        unsigned short u[8] = { f2bu(a.x), f2bu(a.y), f2bu(a.z), f2bu(a.w),
                                f2bu(b.x), f2bu(b.y), f2bu(b.z), f2bu(b.w) };
        *(uint4*)(hsb + i) = *(uint4*)u;
        return;
    }
    const float* src; __hip_bfloat16* dst; int N, kt, nt;
    if (id < 1024)      { src = Wq; dst = WqkvT;                          N = 2048; kt = id >> 5;          nt = id & 31; }
    else if (id < 1536) { src = Wk; dst = WqkvT + (size_t)2048*2048;      N = 1024; kt = (id-1024) >> 4;   nt = (id-1024) & 15; }
    else if (id < 2048) { src = Wv; dst = WqkvT + (size_t)3072*2048;      N = 1024; kt = (id-1536) >> 4;   nt = (id-1536) & 15; }
    else                { src = Wo; dst = WoT;                            N = 2048; kt = (id-2048) >> 5;   nt = (id-2048) & 31; }
    int k0 = kt * 64, n0 = nt * 64;
    int tid = threadIdx.x;
#pragma unroll
    for (int p = 0; p < 2; ++p) {           // phase 1: read rows, cvt, swizzled store
        int c = p*256 + tid; int r = c >> 3, cc = (c & 7) * 8;
        const float* s = src + (size_t)(k0 + r)*N + n0 + cc;
        float4 a = *(const float4*)s;
        float4 b = *(const float4*)(s + 4);
        unsigned w0 = f2bu(a.x) | ((unsigned)f2bu(a.y) << 16);
        unsigned w1 = f2bu(a.z) | ((unsigned)f2bu(a.w) << 16);
        unsigned w2 = f2bu(b.x) | ((unsigned)f2bu(b.y) << 16);
        unsigned w3 = f2bu(b.z) | ((unsigned)f2bu(b.w) << 16);
        int Wb = (cc >> 1) ^ ((r & 7) << 2);        // granule-4 XOR
        tile32[r][Wb+0] = w0; tile32[r][Wb+1] = w1;
        tile32[r][Wb+2] = w2; tile32[r][Wb+3] = w3;
    }
    __syncthreads();
    {   // phase 2: each thread emits out-row pair (2*r2h, 2*r2h+1), 8 cols
        int r2h = tid >> 3;                 // 0..31  (input word-col)
        int c2  = (tid & 7) * 8;            // input-row chunk / out-col chunk
        unsigned lo[4], hi[4];
#pragma unroll
        for (int j = 0; j < 4; ++j) {
            int R0 = c2 + 2*j, R1 = R0 + 1;
            unsigned wa = tile32[R0][r2h ^ ((R0 & 7) << 2)];
            unsigned wb = tile32[R1][r2h ^ ((R1 & 7) << 2)];
            lo[j] = (wa & 0xFFFFu) | (wb << 16);
            hi[j] = (wa >> 16) | (wb & 0xFFFF0000u);
        }
        __hip_bfloat16* d0 = dst + (size_t)(n0 + 2*r2h)*2048 + k0 + c2;
        *(uint4*)d0          = *(uint4*)lo;
        *(uint4*)(d0 + 2048) = *(uint4*)hi;
    }
}

// ---------------------------------------------------------------------------
// GEMM: C[M][N] = A[M][K] * BT[N][K]^T.
// BM=128 x BN=128, BK=64, double-buffered LDS (64 KB), 4 waves (2x2,
// wave-tile 64x64), 2 blocks/CU.  The proven 42-48us/~800TF structure.
// ---------------------------------------------------------------------------
template <typename OT>
__global__ __launch_bounds__(256, 2) void gemm_bt_kernel(
    const __hip_bfloat16* __restrict__ A, const __hip_bfloat16* __restrict__ BT,
    OT* __restrict__ C, int M, int N, int K)
{
    __shared__ __attribute__((aligned(16))) __hip_bfloat16 As[2][128*64];  // 2x16KB
    __shared__ __attribute__((aligned(16))) __hip_bfloat16 Bs[2][128*64];  // 2x16KB
    const int tid  = threadIdx.x;
    const int lane = tid & 63;
    const int wave = tid >> 6;
    const int quad = lane >> 4, l15 = lane & 15;
    const int m0 = blockIdx.y * 128, n0 = blockIdx.x * 128;
    const int wm = (wave >> 1) * 64, wn = (wave & 1) * 64;
    const int sw = l15 & 7;                     // row-parity xor term (lane-const)

    f32x4 acc[4][4] = {};

    auto stage = [&](int b, int k0) {
#pragma unroll
        for (int p = 0; p < 4; ++p) {           // A: 128 rows x 8 slots of 16B
            int L = p*256 + tid;
            int r = L >> 3, s = L & 7;
            int cs = s ^ (r & 7);
            gld16((char*)&As[b][0] + L*16, A + (size_t)(m0 + r)*K + k0 + cs*8);
        }
#pragma unroll
        for (int p = 0; p < 4; ++p) {           // B: 128 rows x 8 slots of 16B
            int L = p*256 + tid;
            int r = L >> 3, s = L & 7;
            int cs = s ^ (r & 7);
            gld16((char*)&Bs[b][0] + L*16, BT + (size_t)(n0 + r)*K + k0 + cs*8);
        }
    };

    const int NT = K >> 6;
    stage(0, 0);
    int cur = 0;
    for (int kt = 0; kt < NT; ++kt, cur ^= 1) {
        __syncthreads();                        // staging for cur done; waves synced
        if (kt + 1 < NT) stage(cur ^ 1, (kt + 1) << 6);
#pragma unroll
        for (int ks = 0; ks < 2; ++ks) {        // two 32-k steps within BK=64
            const int slot = ((ks*4 + quad) ^ sw) * 8;
            bf16x8 af[4], bfr[4];
#pragma unroll
            for (int t = 0; t < 4; ++t) {
                af[t]  = *(const bf16x8*)(&As[cur][0] + (wm + t*16 + l15)*64 + slot);
                bfr[t] = *(const bf16x8*)(&Bs[cur][0] + (wn + t*16 + l15)*64 + slot);
            }
#pragma unroll
            for (int mt = 0; mt < 4; ++mt)
#pragma unroll
                for (int nt = 0; nt < 4; ++nt)
                    acc[mt][nt] = __builtin_amdgcn_mfma_f32_16x16x32_bf16(af[mt], bfr[nt], acc[mt][nt], 0, 0, 0);
        }
    }
#pragma unroll
    for (int mt = 0; mt < 4; ++mt)
#pragma unroll
        for (int nt = 0; nt < 4; ++nt)
#pragma unroll
            for (int r = 0; r < 4; ++r) {
                int row = m0 + wm + mt*16 + quad*4 + r;
                int col = n0 + wn + nt*16 + l15;
                if constexpr (__is_same(OT, float))
                    C[(size_t)row*N + col] = acc[mt][nt][r];
                else
                    C[(size_t)row*N + col] = __float2bfloat16(acc[mt][nt][r]);
            }
}

// ---------------------------------------------------------------------------
// GEMM, 64x128 tile (output projection, M=N=2048): BM=64 x BN=128, BK=64,
// 48 KB LDS, 4 waves (2x2, wave-tile 32x64), grid 512 blocks = 2 blk/CU.
// ---------------------------------------------------------------------------
template <typename OT>
__global__ __launch_bounds__(256, 2) void gemm_bt64_kernel(
    const __hip_bfloat16* __restrict__ A, const __hip_bfloat16* __restrict__ BT,
    OT* __restrict__ C, int M, int N, int K)
{
    __shared__ __attribute__((aligned(16))) __hip_bfloat16 As[2][64*64];   // 2x8KB
    __shared__ __attribute__((aligned(16))) __hip_bfloat16 Bs[2][128*64];  // 2x16KB
    const int tid  = threadIdx.x;
    const int lane = tid & 63;
    const int wave = tid >> 6;
    const int quad = lane >> 4, l15 = lane & 15;
    const int m0 = blockIdx.y * 64, n0 = blockIdx.x * 128;
    const int wm = (wave >> 1) * 32, wn = (wave & 1) * 64;
    const int sw = l15 & 7;                     // row-parity xor term (lane-const)

    f32x4 acc[2][4] = {};

    auto stage = [&](int b, int k0) {
#pragma unroll
        for (int p = 0; p < 2; ++p) {           // A: 64 rows x 8 slots of 16B
            int L = p*256 + tid;
            int r = L >> 3, s = L & 7;
            int cs = s ^ (r & 7);
            gld16((char*)&As[b][0] + L*16, A + (size_t)(m0 + r)*K + k0 + cs*8);
        }
#pragma unroll
        for (int p = 0; p < 4; ++p) {           // B: 128 rows x 8 slots of 16B
            int L = p*256 + tid;
            int r = L >> 3, s = L & 7;
            int cs = s ^ (r & 7);
            gld16((char*)&Bs[b][0] + L*16, BT + (size_t)(n0 + r)*K + k0 + cs*8);
        }
    };

    const int NT = K >> 6;
    stage(0, 0);
    int cur = 0;
    for (int kt = 0; kt < NT; ++kt, cur ^= 1) {
        __syncthreads();                        // staging for cur done; waves synced
        if (kt + 1 < NT) stage(cur ^ 1, (kt + 1) << 6);
#pragma unroll
        for (int ks = 0; ks < 2; ++ks) {        // two 32-k steps within BK=64
            const int slot = ((ks*4 + quad) ^ sw) * 8;
            bf16x8 af[2], bfr[4];
#pragma unroll
            for (int t = 0; t < 2; ++t)
                af[t]  = *(const bf16x8*)(&As[cur][0] + (wm + t*16 + l15)*64 + slot);
#pragma unroll
            for (int t = 0; t < 4; ++t)
                bfr[t] = *(const bf16x8*)(&Bs[cur][0] + (wn + t*16 + l15)*64 + slot);
#pragma unroll
            for (int mt = 0; mt < 2; ++mt)
#pragma unroll
                for (int nt = 0; nt < 4; ++nt)
                    acc[mt][nt] = __builtin_amdgcn_mfma_f32_16x16x32_bf16(af[mt], bfr[nt], acc[mt][nt], 0, 0, 0);
        }
    }
#pragma unroll
    for (int mt = 0; mt < 2; ++mt)
#pragma unroll
        for (int nt = 0; nt < 4; ++nt)
#pragma unroll
            for (int r = 0; r < 4; ++r) {
                int row = m0 + wm + mt*16 + quad*4 + r;
                int col = n0 + wn + nt*16 + l15;
                if constexpr (__is_same(OT, float))
                    C[(size_t)row*N + col] = acc[mt][nt][r];
                else
                    C[(size_t)row*N + col] = __float2bfloat16(acc[mt][nt][r]);
            }
}

// ---------------------------------------------------------------------------
// Fused: RMSNorm+RoPE on Q,K rows of QKVraw (blocks 0..2047, one s each)
//        AND V transpose QKVraw -> Vt (blocks 2048..2559, 64x64 tiles,
//        conflict-free u32-pair scheme as in trans_cvt).
// Q output pre-scaled by QK_SCALE*log2(e) (attention uses exp2 directly).
// ---------------------------------------------------------------------------
__global__ __launch_bounds__(256) void rms_vt_kernel(
    const __hip_bfloat16* __restrict__ qkv,
    const float* __restrict__ cosb, const float* __restrict__ sinb,
    const float* __restrict__ qsc,  const float* __restrict__ ksc,
    __hip_bfloat16* __restrict__ Qn, __hip_bfloat16* __restrict__ Kn,
    __hip_bfloat16* __restrict__ Vt)
{
    __shared__ __attribute__((aligned(16))) unsigned tile32[64][37];
    int id = blockIdx.x;
    if (id >= 2048) {   // ---- V transpose tile ----
        int t  = id - 2048;                 // 512 tiles: 32 (s) x 16 (v)
        int s0 = (t & 31) * 64;
        int v0 = (t >> 5) * 64;
        int tid = threadIdx.x;
#pragma unroll
        for (int p = 0; p < 2; ++p) {       // phase 1: swizzled u32 store
            int c = p*256 + tid; int r = c >> 3, cc = (c & 7) * 8;
            uint4 v = *(const uint4*)(qkv + (size_t)(s0 + r)*4096 + 3072 + v0 + cc);
            int Wb = (cc >> 1) ^ ((r & 7) << 2);
            tile32[r][Wb+0] = v.x; tile32[r][Wb+1] = v.y;
            tile32[r][Wb+2] = v.z; tile32[r][Wb+3] = v.w;
        }
        __syncthreads();
        {   // phase 2: out-row pair per thread
            int r2h = tid >> 3;
            int c2  = (tid & 7) * 8;
            unsigned lo[4], hi[4];
#pragma unroll
            for (int j = 0; j < 4; ++j) {
                int R0 = c2 + 2*j, R1 = R0 + 1;
                unsigned wa = tile32[R0][r2h ^ ((R0 & 7) << 2)];
                unsigned wb = tile32[R1][r2h ^ ((R1 & 7) << 2)];
                lo[j] = (wa & 0xFFFFu) | (wb << 16);
                hi[j] = (wa >> 16) | (wb & 0xFFFF0000u);
            }
            __hip_bfloat16* d0 = Vt + (size_t)(v0 + 2*r2h)*2048 + s0 + c2;
            *(uint4*)d0          = *(uint4*)lo;
            *(uint4*)(d0 + 2048) = *(uint4*)hi;
        }
        return;
    }
    // ---- RMSNorm + RoPE ----
    int s = id;
    int wave = threadIdx.x >> 6, lane = threadIdx.x & 63;
    float c1 = cosb[s*128 + lane];
    float c2 = cosb[s*128 + 64 + lane];
    float s1 = sinb[s*128 + lane];
    float s2 = sinb[s*128 + 64 + lane];
    for (int u = wave; u < 24; u += 4) {
        bool isq = (u < 16);
        int h = isq ? u : u - 16;
        const __hip_bfloat16* x = qkv + (size_t)s*4096 + (isq ? h*128 : 2048 + h*128);
        float x1 = (float)x[lane], x2 = (float)x[lane + 64];
        float ss = x1*x1 + x2*x2;
#pragma unroll
        for (int off = 32; off; off >>= 1) ss += __shfl_xor(ss, off);
        float r = rsqrtf(ss * (1.0f/128.0f) + RMS_EPS);
        if (isq) r *= QK_SCALE_L2E;        // fold attn scale + log2e into Q
        const float* sc = isq ? qsc : ksc;
        float y1 = x1 * r * sc[lane];
        float y2 = x2 * r * sc[lane + 64];
        float o1 = y1*c1 - y2*s1;   // d < 64:  x*c - x[d+64]*s
        float o2 = y2*c2 + y1*s2;   // d >= 64: x*c + x[d-64]*s
        __hip_bfloat16* dst = isq ? (Qn + (size_t)s*2048 + h*128)
                                  : (Kn + (size_t)s*1024 + h*128);
        dst[lane]      = __float2bfloat16(o1);
        dst[lane + 64] = __float2bfloat16(o2);
    }
}

// ---------------------------------------------------------------------------
// Flash attention, sliding-window causal — m97-style LDS staging.
//  * Block = 4 waves x 16 q-rows = 64 q-rows of one head; grid 512 (2 blk/CU).
//  * XCD-aware head mapping: XCD x (= bx%8) serves only kv-head x ->
//    its K+V (0.75 MB) stays L2-resident per XCD (T1).
//  * K/V tiles staged into double-buffered LDS via global_load_lds width=16.
//  * XOR-swizzled LDS layouts; one barrier per tile; next staging issued
//    right after it (double buffer overlaps full tile compute).
//  * T5: setprio(1) around the QK^T and PV MFMA clusters -- co-resident
//    blocks are at different window phases, so priority keeps the matrix
//    pipe fed while the sibling block drains staging (m191 precedent).
//  * No online max (scores bounded by RMS-norm); p=exp2(s), per-lane row
//    sums, single cross-lane reduce in epilogue.
// ---------------------------------------------------------------------------
__global__ __launch_bounds__(256, 2) void attn_kernel(
    const __hip_bfloat16* __restrict__ Qn,  // [S][2048], pre-scaled (log2 domain)
    const __hip_bfloat16* __restrict__ Kn,  // [S][1024]
    const __hip_bfloat16* __restrict__ Vt,  // [1024][S]
    __hip_bfloat16* __restrict__ O)         // [S][2048]
{
    __shared__ __attribute__((aligned(16))) __hip_bfloat16 Ksm[2][64*128];  // 2x16KB
    __shared__ __attribute__((aligned(16))) __hip_bfloat16 Vsm[2][128*64];  // 2x16KB
    __shared__ __attribute__((aligned(16))) __hip_bfloat16 P[4][16][76];

    const int bx   = blockIdx.x;
    const int h    = ((bx & 7) << 1) | ((bx >> 3) & 1);   // XCD bx%8 -> kv-head bx%8
    const int qb   = 31 - (bx >> 4);          // long-window blocks dispatched first
    const int i0   = qb * 64;
    const int hk   = h >> 1;
    const int tid  = threadIdx.x, wave = tid >> 6, lane = tid & 63;
    const int quad = lane >> 4, l15 = lane & 15;
    const int ib   = i0 + wave * 16;

    const __hip_bfloat16* Kh = Kn + hk * HDIM;              // row stride 1024
    const __hip_bfloat16* Vh = Vt + (size_t)(hk * HDIM) * 2048;

    // Q fragments (A-operand), fixed for the block
    bf16x8 qf[4];
    const __hip_bfloat16* qbase = Qn + (size_t)(ib + l15)*2048 + h*HDIM + quad*8;
#pragma unroll
    for (int kk = 0; kk < 4; ++kk) qf[kk] = *(const bf16x8*)(qbase + kk*32);

    f32x4 o[8] = {};
    float lrow[4] = {0.f, 0.f, 0.f, 0.f};

    int j_lo = i0 - WIN; if (j_lo < 0) j_lo = 0;
    const int jstart = j_lo & ~63;
    const int jend   = i0;                    // diagonal tile start

    // ---- cooperative staging of one (K,V) tile pair into buffer b ----
    auto stage = [&](int b, int j0) {
#pragma unroll
        for (int p = 0; p < 4; ++p) {         // K: 64 rows x 16 chunks of 16B
            int L = p*256 + tid;
            int r = L >> 4;
            int c = (L & 15) ^ (r & 15);      // XOR swizzle
            gld16((char*)&Ksm[b][0] + L*16, Kh + (size_t)(j0 + r)*1024 + c*8);
        }
#pragma unroll
        for (int p = 0; p < 4; ++p) {         // V: 128 d-rows x 8 chunks of 16B
            int L = p*256 + tid;
            int dv = L >> 3;
            int c = (L & 7) ^ (dv & 7);       // XOR swizzle
            gld16((char*)&Vsm[b][0] + L*16, Vh + (size_t)dv*2048 + j0 + c*8);
        }
    };

    stage(0, jstart);
    int cur = 0;
    for (int j0 = jstart; j0 <= jend; j0 += 64, cur ^= 1) {
        __syncthreads();                      // drains staging vmcnt + syncs buffers
        if (j0 + 64 <= jend) stage(cur ^ 1, j0 + 64);

        // ---- S = Q K^T (16 x 64 per wave), frags from swizzled LDS ----
        f32x4 sacc[4] = {};
        __builtin_amdgcn_s_setprio(1);
#pragma unroll
        for (int nt = 0; nt < 4; ++nt) {
            const int r = nt*16 + l15;
#pragma unroll
            for (int kk = 0; kk < 4; ++kk) {
                const int cc = (kk*4 + quad) ^ l15;   // swizzled chunk
                bf16x8 kfr = *(const bf16x8*)(&Ksm[cur][0] + r*128 + cc*8);
                sacc[nt] = __builtin_amdgcn_mfma_f32_16x16x32_bf16(qf[kk], kfr, sacc[nt], 0, 0, 0);
            }
        }
        __builtin_amdgcn_s_setprio(0);

        // ---- p = exp2(s), P write, per-lane row-sum ----
        const bool need_mask = (j0 + 63 > ib) || (j0 < ib + 15 - WIN);
        if (need_mask) {
#pragma unroll
            for (int nt = 0; nt < 4; ++nt) {
                int j = j0 + nt*16 + l15;
#pragma unroll
                for (int r = 0; r < 4; ++r) {
                    int i = ib + quad*4 + r;
                    bool valid = (j <= i) && (i - j <= WIN);
                    float p = valid ? __builtin_exp2f(sacc[nt][r]) : 0.f;
                    lrow[r] += p;
                    P[wave][quad*4 + r][nt*16 + l15] = __float2bfloat16(p);
                }
            }
        } else {
#pragma unroll
            for (int nt = 0; nt < 4; ++nt)
#pragma unroll
                for (int r = 0; r < 4; ++r) {
                    float p = __builtin_exp2f(sacc[nt][r]);
                    lrow[r] += p;
                    P[wave][quad*4 + r][nt*16 + l15] = __float2bfloat16(p);
                }
        }

        // ---- O += P V (P per-wave, lgkm-ordered; V frags from swizzled LDS) ----
        __builtin_amdgcn_s_setprio(1);
#pragma unroll
        for (int ks = 0; ks < 2; ++ks) {
            bf16x8 pf = *(const bf16x8*)&P[wave][l15][ks*32 + quad*8];
#pragma unroll
            for (int dt = 0; dt < 8; ++dt) {
                const int dv = dt*16 + l15;
                const int cc = (ks*4 + quad) ^ (l15 & 7);
                bf16x8 vfr = *(const bf16x8*)(&Vsm[cur][0] + dv*64 + cc*8);
                o[dt] = __builtin_amdgcn_mfma_f32_16x16x32_bf16(pf, vfr, o[dt], 0, 0, 0);
            }
        }
        __builtin_amdgcn_s_setprio(0);
    }

    // ---- epilogue: single cross-lane reduce of lrow, normalize, store ----
#pragma unroll
    for (int r = 0; r < 4; ++r) {
        lrow[r] += __shfl_xor(lrow[r], 1);
        lrow[r] += __shfl_xor(lrow[r], 2);
        lrow[r] += __shfl_xor(lrow[r], 4);
        lrow[r] += __shfl_xor(lrow[r], 8);
        float inv = 1.0f / lrow[r];
        int row = ib + quad*4 + r;
#pragma unroll
        for (int dt = 0; dt < 8; ++dt)
            O[(size_t)row*2048 + h*HDIM + dt*16 + l15] = __float2bfloat16(o[dt][r] * inv);
    }
}

// ---------------------------------------------------------------------------
extern "C" void kernel_launch(void* const* d_in, const int* in_sizes, int n_in,
                              void* d_out, int out_size, void* d_ws, size_t ws_size,
                              hipStream_t stream)
{
    (void)in_sizes; (void)n_in; (void)out_size; (void)ws_size;
    const float* hs   = (const float*)d_in[0];
    const float* cosb = (const float*)d_in[1];
    const float* sinb = (const float*)d_in[2];
    const float* Wq   = (const float*)d_in[3];
    const float* Wk   = (const float*)d_in[4];
    const float* Wv   = (const float*)d_in[5];
    const float* Wo   = (const float*)d_in[6];
    const float* qs   = (const float*)d_in[7];
    const float* ks   = (const float*)d_in[8];

    char* ws = (char*)d_ws;
    __hip_bfloat16* WqkvT = (__hip_bfloat16*)(ws);
    __hip_bfloat16* WoT   = (__hip_bfloat16*)(ws + (16u << 20));
    __hip_bfloat16* QKV   = (__hip_bfloat16*)(ws + (24u << 20));
    __hip_bfloat16* Qn    = (__hip_bfloat16*)(ws + (40u << 20));
    __hip_bfloat16* Kn    = (__hip_bfloat16*)(ws + (48u << 20));
    __hip_bfloat16* Vt    = (__hip_bfloat16*)(ws + (52u << 20));
    __hip_bfloat16* hsb   = (__hip_bfloat16*)(ws + (56u << 20)); // overlaid with AT
    __hip_bfloat16* AT    = (__hip_bfloat16*)(ws + (56u << 20)); // disjoint liveness

    trans_cvt_kernel<<<dim3(5120), dim3(256), 0, stream>>>(Wq, Wk, Wv, Wo, hs, WqkvT, WoT, hsb);
    gemm_bt_kernel<__hip_bfloat16><<<dim3(32, 16), dim3(256), 0, stream>>>(hsb, WqkvT, QKV, 2048, 4096, 2048);
    rms_vt_kernel<<<dim3(2560), dim3(256), 0, stream>>>(QKV, cosb, sinb, qs, ks, Qn, Kn, Vt);
    attn_kernel<<<dim3(512), dim3(256), 0, stream>>>(Qn, Kn, Vt, AT);
    gemm_bt64_kernel<float><<<dim3(16, 32), dim3(256), 0, stream>>>(AT, WoT, (float*)d_out, 2048, 2048, 2048);
}

// Round 10
// 218.093 us; speedup vs baseline: 1.2203x; 1.0113x over previous
//
#include <hip/hip_runtime.h>
#include <hip/hip_bf16.h>
#include <cmath>

// I/O: all inputs float32 (per reference setup_inputs), output float32.
// Internal compute: bf16 MFMA with fp32 accumulation.
//
// Workspace layout (64 MB total):
//  [0,16M)   WqkvT  [4096][2048] bf16   (rows: 0-2047 WqT, 2048-3071 WkT, 3072-4095 WvT)
//  [16,24M)  WoT    [2048][2048] bf16
//  [24,40M)  QKVraw [2048][4096] bf16
//  [40,48M)  Qn     [2048][2048] bf16   (post rms+rope, pre-scaled by QK_SCALE*log2e)
//  [48,52M)  Kn     [2048][1024] bf16
//  [52,56M)  Vt     [1024][2048] bf16   ([hkv*128 d][s])
//  [56,64M)  hsb    [2048][2048] bf16   (live: kernels 1-2)   }  overlaid,
//  [56,64M)  AT     [2048][2048] bf16   (live: kernels 4-5)   }  disjoint liveness
//
// R10 = R5 (best known, 218.7us; R9 setprio was noise -> dropped) + gemm2
// retile 64x128 -> 64x64.  Ledger: gemm2 at 39us/440TF runs at 3.8x its
// LDS-pipe bound (2925 vs 770 cyc/BK) -> latency/barrier-bound, not
// bandwidth-bound.  Same lever as R3: more co-resident blocks to hide the
// staging drain.  64x64 tile, 32KB LDS, launch_bounds(256,4) -> 1024
// blocks = 4/CU (LDS 128<=160, VGPR 88<=128).

typedef __bf16 bf16x8 __attribute__((ext_vector_type(8)));
typedef float  f32x4  __attribute__((ext_vector_type(4)));

#define S_LEN    2048
#define NH       16
#define NKV      8
#define HDIM     128
#define WIN      1024
// QK_SCALE * log2(e): scores computed directly in log2 domain -> exp2
#define QK_SCALE_L2E 0.12751744595f
#define RMS_EPS  1e-6f

__device__ __forceinline__ void gld16(void* lds, const void* g) {
    __builtin_amdgcn_global_load_lds(
        (const __attribute__((address_space(1))) unsigned int*)g,
        (__attribute__((address_space(3))) unsigned int*)lds, 16, 0, 0);
}

__device__ __forceinline__ unsigned short f2bu(float x) {
    __hip_bfloat16 h = __float2bfloat16(x);
    return *(unsigned short*)&h;
}

// ---------------------------------------------------------------------------
// Fused: weight transpose + f32->bf16 (blocks 0..3071)  AND
//        hidden_states f32->bf16 convert (blocks 3072..5119).
// Conflict-free u32-pair transpose tile (see R5 notes).
// ---------------------------------------------------------------------------
__global__ __launch_bounds__(256) void trans_cvt_kernel(
    const float* __restrict__ Wq, const float* __restrict__ Wk,
    const float* __restrict__ Wv, const float* __restrict__ Wo,
    const float* __restrict__ hs,
    __hip_bfloat16* __restrict__ WqkvT, __hip_bfloat16* __restrict__ WoT,
    __hip_bfloat16* __restrict__ hsb)
{
    __shared__ __attribute__((aligned(16))) unsigned tile32[64][37];
    int id = blockIdx.x;
    if (id >= 3072) {   // ---- hidden_states convert: 8 elems/thread ----
        size_t i = ((size_t)(id - 3072) * 256 + threadIdx.x) * 8;
        float4 a = *(const float4*)(hs + i);
        float4 b = *(const float4*)(hs + i + 4);
        unsigned short u[8] = { f2bu(a.x), f2bu(a.y), f2bu(a.z), f2bu(a.w),
                                f2bu(b.x), f2bu(b.y), f2bu(b.z), f2bu(b.w) };
        *(uint4*)(hsb + i) = *(uint4*)u;
        return;
    }
    const float* src; __hip_bfloat16* dst; int N, kt, nt;
    if (id < 1024)      { src = Wq; dst = WqkvT;                          N = 2048; kt = id >> 5;          nt = id & 31; }
    else if (id < 1536) { src = Wk; dst = WqkvT + (size_t)2048*2048;      N = 1024; kt = (id-1024) >> 4;   nt = (id-1024) & 15; }
    else if (id < 2048) { src = Wv; dst = WqkvT + (size_t)3072*2048;      N = 1024; kt = (id-1536) >> 4;   nt = (id-1536) & 15; }
    else                { src = Wo; dst = WoT;                            N = 2048; kt = (id-2048) >> 5;   nt = (id-2048) & 31; }
    int k0 = kt * 64, n0 = nt * 64;
    int tid = threadIdx.x;
#pragma unroll
    for (int p = 0; p < 2; ++p) {           // phase 1: read rows, cvt, swizzled store
        int c = p*256 + tid; int r = c >> 3, cc = (c & 7) * 8;
        const float* s = src + (size_t)(k0 + r)*N + n0 + cc;
        float4 a = *(const float4*)s;
        float4 b = *(const float4*)(s + 4);
        unsigned w0 = f2bu(a.x) | ((unsigned)f2bu(a.y) << 16);
        unsigned w1 = f2bu(a.z) | ((unsigned)f2bu(a.w) << 16);
        unsigned w2 = f2bu(b.x) | ((unsigned)f2bu(b.y) << 16);
        unsigned w3 = f2bu(b.z) | ((unsigned)f2bu(b.w) << 16);
        int Wb = (cc >> 1) ^ ((r & 7) << 2);        // granule-4 XOR
        tile32[r][Wb+0] = w0; tile32[r][Wb+1] = w1;
        tile32[r][Wb+2] = w2; tile32[r][Wb+3] = w3;
    }
    __syncthreads();
    {   // phase 2: each thread emits out-row pair (2*r2h, 2*r2h+1), 8 cols
        int r2h = tid >> 3;                 // 0..31  (input word-col)
        int c2  = (tid & 7) * 8;            // input-row chunk / out-col chunk
        unsigned lo[4], hi[4];
#pragma unroll
        for (int j = 0; j < 4; ++j) {
            int R0 = c2 + 2*j, R1 = R0 + 1;
            unsigned wa = tile32[R0][r2h ^ ((R0 & 7) << 2)];
            unsigned wb = tile32[R1][r2h ^ ((R1 & 7) << 2)];
            lo[j] = (wa & 0xFFFFu) | (wb << 16);
            hi[j] = (wa >> 16) | (wb & 0xFFFF0000u);
        }
        __hip_bfloat16* d0 = dst + (size_t)(n0 + 2*r2h)*2048 + k0 + c2;
        *(uint4*)d0          = *(uint4*)lo;
        *(uint4*)(d0 + 2048) = *(uint4*)hi;
    }
}

// ---------------------------------------------------------------------------
// GEMM: C[M][N] = A[M][K] * BT[N][K]^T.
// BM=128 x BN=128, BK=64, double-buffered LDS (64 KB), 4 waves (2x2,
// wave-tile 64x64), 2 blocks/CU.  The proven 42-48us/~800TF structure.
// ---------------------------------------------------------------------------
template <typename OT>
__global__ __launch_bounds__(256, 2) void gemm_bt_kernel(
    const __hip_bfloat16* __restrict__ A, const __hip_bfloat16* __restrict__ BT,
    OT* __restrict__ C, int M, int N, int K)
{
    __shared__ __attribute__((aligned(16))) __hip_bfloat16 As[2][128*64];  // 2x16KB
    __shared__ __attribute__((aligned(16))) __hip_bfloat16 Bs[2][128*64];  // 2x16KB
    const int tid  = threadIdx.x;
    const int lane = tid & 63;
    const int wave = tid >> 6;
    const int quad = lane >> 4, l15 = lane & 15;
    const int m0 = blockIdx.y * 128, n0 = blockIdx.x * 128;
    const int wm = (wave >> 1) * 64, wn = (wave & 1) * 64;
    const int sw = l15 & 7;                     // row-parity xor term (lane-const)

    f32x4 acc[4][4] = {};

    auto stage = [&](int b, int k0) {
#pragma unroll
        for (int p = 0; p < 4; ++p) {           // A: 128 rows x 8 slots of 16B
            int L = p*256 + tid;
            int r = L >> 3, s = L & 7;
            int cs = s ^ (r & 7);
            gld16((char*)&As[b][0] + L*16, A + (size_t)(m0 + r)*K + k0 + cs*8);
        }
#pragma unroll
        for (int p = 0; p < 4; ++p) {           // B: 128 rows x 8 slots of 16B
            int L = p*256 + tid;
            int r = L >> 3, s = L & 7;
            int cs = s ^ (r & 7);
            gld16((char*)&Bs[b][0] + L*16, BT + (size_t)(n0 + r)*K + k0 + cs*8);
        }
    };

    const int NT = K >> 6;
    stage(0, 0);
    int cur = 0;
    for (int kt = 0; kt < NT; ++kt, cur ^= 1) {
        __syncthreads();                        // staging for cur done; waves synced
        if (kt + 1 < NT) stage(cur ^ 1, (kt + 1) << 6);
#pragma unroll
        for (int ks = 0; ks < 2; ++ks) {        // two 32-k steps within BK=64
            const int slot = ((ks*4 + quad) ^ sw) * 8;
            bf16x8 af[4], bfr[4];
#pragma unroll
            for (int t = 0; t < 4; ++t) {
                af[t]  = *(const bf16x8*)(&As[cur][0] + (wm + t*16 + l15)*64 + slot);
                bfr[t] = *(const bf16x8*)(&Bs[cur][0] + (wn + t*16 + l15)*64 + slot);
            }
#pragma unroll
            for (int mt = 0; mt < 4; ++mt)
#pragma unroll
                for (int nt = 0; nt < 4; ++nt)
                    acc[mt][nt] = __builtin_amdgcn_mfma_f32_16x16x32_bf16(af[mt], bfr[nt], acc[mt][nt], 0, 0, 0);
        }
    }
#pragma unroll
    for (int mt = 0; mt < 4; ++mt)
#pragma unroll
        for (int nt = 0; nt < 4; ++nt)
#pragma unroll
            for (int r = 0; r < 4; ++r) {
                int row = m0 + wm + mt*16 + quad*4 + r;
                int col = n0 + wn + nt*16 + l15;
                if constexpr (__is_same(OT, float))
                    C[(size_t)row*N + col] = acc[mt][nt][r];
                else
                    C[(size_t)row*N + col] = __float2bfloat16(acc[mt][nt][r]);
            }
}

// ---------------------------------------------------------------------------
// GEMM, 64x64 tile (output projection, M=N=2048): BM=BN=64, BK=64, 32 KB
// LDS, 4 waves (2x2, wave-tile 32x32), grid (32,32) = 1024 blocks = 4/CU
// (launch_bounds(256,4); VGPR 88 <= 128).  gemm2 was latency-bound at
// 64x128 (2925 cyc/BK vs 770 LDS bound, 440 TF): 4-way block overlap
// hides the staging drain the same way R3's retile did.
// ---------------------------------------------------------------------------
template <typename OT>
__global__ __launch_bounds__(256, 4) void gemm_bt64_kernel(
    const __hip_bfloat16* __restrict__ A, const __hip_bfloat16* __restrict__ BT,
    OT* __restrict__ C, int M, int N, int K)
{
    __shared__ __attribute__((aligned(16))) __hip_bfloat16 As[2][64*64];   // 2x8KB
    __shared__ __attribute__((aligned(16))) __hip_bfloat16 Bs[2][64*64];   // 2x8KB
    const int tid  = threadIdx.x;
    const int lane = tid & 63;
    const int wave = tid >> 6;
    const int quad = lane >> 4, l15 = lane & 15;
    const int m0 = blockIdx.y * 64, n0 = blockIdx.x * 64;
    const int wm = (wave >> 1) * 32, wn = (wave & 1) * 32;
    const int sw = l15 & 7;                     // row-parity xor term (lane-const)

    f32x4 acc[2][2] = {};

    auto stage = [&](int b, int k0) {
#pragma unroll
        for (int p = 0; p < 2; ++p) {           // A: 64 rows x 8 slots of 16B
            int L = p*256 + tid;
            int r = L >> 3, s = L & 7;
            int cs = s ^ (r & 7);
            gld16((char*)&As[b][0] + L*16, A + (size_t)(m0 + r)*K + k0 + cs*8);
        }
#pragma unroll
        for (int p = 0; p < 2; ++p) {           // B: 64 rows x 8 slots of 16B
            int L = p*256 + tid;
            int r = L >> 3, s = L & 7;
            int cs = s ^ (r & 7);
            gld16((char*)&Bs[b][0] + L*16, BT + (size_t)(n0 + r)*K + k0 + cs*8);
        }
    };

    const int NT = K >> 6;
    stage(0, 0);
    int cur = 0;
    for (int kt = 0; kt < NT; ++kt, cur ^= 1) {
        __syncthreads();                        // staging for cur done; waves synced
        if (kt + 1 < NT) stage(cur ^ 1, (kt + 1) << 6);
#pragma unroll
        for (int ks = 0; ks < 2; ++ks) {        // two 32-k steps within BK=64
            const int slot = ((ks*4 + quad) ^ sw) * 8;
            bf16x8 af[2], bfr[2];
#pragma unroll
            for (int t = 0; t < 2; ++t) {
                af[t]  = *(const bf16x8*)(&As[cur][0] + (wm + t*16 + l15)*64 + slot);
                bfr[t] = *(const bf16x8*)(&Bs[cur][0] + (wn + t*16 + l15)*64 + slot);
            }
#pragma unroll
            for (int mt = 0; mt < 2; ++mt)
#pragma unroll
                for (int nt = 0; nt < 2; ++nt)
                    acc[mt][nt] = __builtin_amdgcn_mfma_f32_16x16x32_bf16(af[mt], bfr[nt], acc[mt][nt], 0, 0, 0);
        }
    }
#pragma unroll
    for (int mt = 0; mt < 2; ++mt)
#pragma unroll
        for (int nt = 0; nt < 2; ++nt)
#pragma unroll
            for (int r = 0; r < 4; ++r) {
                int row = m0 + wm + mt*16 + quad*4 + r;
                int col = n0 + wn + nt*16 + l15;
                if constexpr (__is_same(OT, float))
                    C[(size_t)row*N + col] = acc[mt][nt][r];
                else
                    C[(size_t)row*N + col] = __float2bfloat16(acc[mt][nt][r]);
            }
}

// ---------------------------------------------------------------------------
// Fused: RMSNorm+RoPE on Q,K rows of QKVraw (blocks 0..2047, one s each)
//        AND V transpose QKVraw -> Vt (blocks 2048..2559, 64x64 tiles,
//        conflict-free u32-pair scheme as in trans_cvt).
// Q output pre-scaled by QK_SCALE*log2(e) (attention uses exp2 directly).
// ---------------------------------------------------------------------------
__global__ __launch_bounds__(256) void rms_vt_kernel(
    const __hip_bfloat16* __restrict__ qkv,
    const float* __restrict__ cosb, const float* __restrict__ sinb,
    const float* __restrict__ qsc,  const float* __restrict__ ksc,
    __hip_bfloat16* __restrict__ Qn, __hip_bfloat16* __restrict__ Kn,
    __hip_bfloat16* __restrict__ Vt)
{
    __shared__ __attribute__((aligned(16))) unsigned tile32[64][37];
    int id = blockIdx.x;
    if (id >= 2048) {   // ---- V transpose tile ----
        int t  = id - 2048;                 // 512 tiles: 32 (s) x 16 (v)
        int s0 = (t & 31) * 64;
        int v0 = (t >> 5) * 64;
        int tid = threadIdx.x;
#pragma unroll
        for (int p = 0; p < 2; ++p) {       // phase 1: swizzled u32 store
            int c = p*256 + tid; int r = c >> 3, cc = (c & 7) * 8;
            uint4 v = *(const uint4*)(qkv + (size_t)(s0 + r)*4096 + 3072 + v0 + cc);
            int Wb = (cc >> 1) ^ ((r & 7) << 2);
            tile32[r][Wb+0] = v.x; tile32[r][Wb+1] = v.y;
            tile32[r][Wb+2] = v.z; tile32[r][Wb+3] = v.w;
        }
        __syncthreads();
        {   // phase 2: out-row pair per thread
            int r2h = tid >> 3;
            int c2  = (tid & 7) * 8;
            unsigned lo[4], hi[4];
#pragma unroll
            for (int j = 0; j < 4; ++j) {
                int R0 = c2 + 2*j, R1 = R0 + 1;
                unsigned wa = tile32[R0][r2h ^ ((R0 & 7) << 2)];
                unsigned wb = tile32[R1][r2h ^ ((R1 & 7) << 2)];
                lo[j] = (wa & 0xFFFFu) | (wb << 16);
                hi[j] = (wa >> 16) | (wb & 0xFFFF0000u);
            }
            __hip_bfloat16* d0 = Vt + (size_t)(v0 + 2*r2h)*2048 + s0 + c2;
            *(uint4*)d0          = *(uint4*)lo;
            *(uint4*)(d0 + 2048) = *(uint4*)hi;
        }
        return;
    }
    // ---- RMSNorm + RoPE ----
    int s = id;
    int wave = threadIdx.x >> 6, lane = threadIdx.x & 63;
    float c1 = cosb[s*128 + lane];
    float c2 = cosb[s*128 + 64 + lane];
    float s1 = sinb[s*128 + lane];
    float s2 = sinb[s*128 + 64 + lane];
    for (int u = wave; u < 24; u += 4) {
        bool isq = (u < 16);
        int h = isq ? u : u - 16;
        const __hip_bfloat16* x = qkv + (size_t)s*4096 + (isq ? h*128 : 2048 + h*128);
        float x1 = (float)x[lane], x2 = (float)x[lane + 64];
        float ss = x1*x1 + x2*x2;
#pragma unroll
        for (int off = 32; off; off >>= 1) ss += __shfl_xor(ss, off);
        float r = rsqrtf(ss * (1.0f/128.0f) + RMS_EPS);
        if (isq) r *= QK_SCALE_L2E;        // fold attn scale + log2e into Q
        const float* sc = isq ? qsc : ksc;
        float y1 = x1 * r * sc[lane];
        float y2 = x2 * r * sc[lane + 64];
        float o1 = y1*c1 - y2*s1;   // d < 64:  x*c - x[d+64]*s
        float o2 = y2*c2 + y1*s2;   // d >= 64: x*c + x[d-64]*s
        __hip_bfloat16* dst = isq ? (Qn + (size_t)s*2048 + h*128)
                                  : (Kn + (size_t)s*1024 + h*128);
        dst[lane]      = __float2bfloat16(o1);
        dst[lane + 64] = __float2bfloat16(o2);
    }
}

// ---------------------------------------------------------------------------
// Flash attention, sliding-window causal — m97-style LDS staging.
//  * Block = 4 waves x 16 q-rows = 64 q-rows of one head; grid 512 (2 blk/CU).
//  * XCD-aware head mapping: XCD x (= bx%8) serves only kv-head x ->
//    its K+V (0.75 MB) stays L2-resident per XCD (T1).
//  * K/V tiles staged into double-buffered LDS via global_load_lds width=16.
//  * XOR-swizzled LDS layouts; one barrier per tile; next staging issued
//    right after it (double buffer overlaps full tile compute).
//  * No online max (scores bounded by RMS-norm); p=exp2(s), per-lane row
//    sums, single cross-lane reduce in epilogue.
// ---------------------------------------------------------------------------
__global__ __launch_bounds__(256, 2) void attn_kernel(
    const __hip_bfloat16* __restrict__ Qn,  // [S][2048], pre-scaled (log2 domain)
    const __hip_bfloat16* __restrict__ Kn,  // [S][1024]
    const __hip_bfloat16* __restrict__ Vt,  // [1024][S]
    __hip_bfloat16* __restrict__ O)         // [S][2048]
{
    __shared__ __attribute__((aligned(16))) __hip_bfloat16 Ksm[2][64*128];  // 2x16KB
    __shared__ __attribute__((aligned(16))) __hip_bfloat16 Vsm[2][128*64];  // 2x16KB
    __shared__ __attribute__((aligned(16))) __hip_bfloat16 P[4][16][76];

    const int bx   = blockIdx.x;
    const int h    = ((bx & 7) << 1) | ((bx >> 3) & 1);   // XCD bx%8 -> kv-head bx%8
    const int qb   = 31 - (bx >> 4);          // long-window blocks dispatched first
    const int i0   = qb * 64;
    const int hk   = h >> 1;
    const int tid  = threadIdx.x, wave = tid >> 6, lane = tid & 63;
    const int quad = lane >> 4, l15 = lane & 15;
    const int ib   = i0 + wave * 16;

    const __hip_bfloat16* Kh = Kn + hk * HDIM;              // row stride 1024
    const __hip_bfloat16* Vh = Vt + (size_t)(hk * HDIM) * 2048;

    // Q fragments (A-operand), fixed for the block
    bf16x8 qf[4];
    const __hip_bfloat16* qbase = Qn + (size_t)(ib + l15)*2048 + h*HDIM + quad*8;
#pragma unroll
    for (int kk = 0; kk < 4; ++kk) qf[kk] = *(const bf16x8*)(qbase + kk*32);

    f32x4 o[8] = {};
    float lrow[4] = {0.f, 0.f, 0.f, 0.f};

    int j_lo = i0 - WIN; if (j_lo < 0) j_lo = 0;
    const int jstart = j_lo & ~63;
    const int jend   = i0;                    // diagonal tile start

    // ---- cooperative staging of one (K,V) tile pair into buffer b ----
    auto stage = [&](int b, int j0) {
#pragma unroll
        for (int p = 0; p < 4; ++p) {         // K: 64 rows x 16 chunks of 16B
            int L = p*256 + tid;
            int r = L >> 4;
            int c = (L & 15) ^ (r & 15);      // XOR swizzle
            gld16((char*)&Ksm[b][0] + L*16, Kh + (size_t)(j0 + r)*1024 + c*8);
        }
#pragma unroll
        for (int p = 0; p < 4; ++p) {         // V: 128 d-rows x 8 chunks of 16B
            int L = p*256 + tid;
            int dv = L >> 3;
            int c = (L & 7) ^ (dv & 7);       // XOR swizzle
            gld16((char*)&Vsm[b][0] + L*16, Vh + (size_t)dv*2048 + j0 + c*8);
        }
    };

    stage(0, jstart);
    int cur = 0;
    for (int j0 = jstart; j0 <= jend; j0 += 64, cur ^= 1) {
        __syncthreads();                      // drains staging vmcnt + syncs buffers
        if (j0 + 64 <= jend) stage(cur ^ 1, j0 + 64);

        // ---- S = Q K^T (16 x 64 per wave), frags from swizzled LDS ----
        f32x4 sacc[4] = {};
#pragma unroll
        for (int nt = 0; nt < 4; ++nt) {
            const int r = nt*16 + l15;
#pragma unroll
            for (int kk = 0; kk < 4; ++kk) {
                const int cc = (kk*4 + quad) ^ l15;   // swizzled chunk
                bf16x8 kfr = *(const bf16x8*)(&Ksm[cur][0] + r*128 + cc*8);
                sacc[nt] = __builtin_amdgcn_mfma_f32_16x16x32_bf16(qf[kk], kfr, sacc[nt], 0, 0, 0);
            }
        }

        // ---- p = exp2(s), P write, per-lane row-sum ----
        const bool need_mask = (j0 + 63 > ib) || (j0 < ib + 15 - WIN);
        if (need_mask) {
#pragma unroll
            for (int nt = 0; nt < 4; ++nt) {
                int j = j0 + nt*16 + l15;
#pragma unroll
                for (int r = 0; r < 4; ++r) {
                    int i = ib + quad*4 + r;
                    bool valid = (j <= i) && (i - j <= WIN);
                    float p = valid ? __builtin_exp2f(sacc[nt][r]) : 0.f;
                    lrow[r] += p;
                    P[wave][quad*4 + r][nt*16 + l15] = __float2bfloat16(p);
                }
            }
        } else {
#pragma unroll
            for (int nt = 0; nt < 4; ++nt)
#pragma unroll
                for (int r = 0; r < 4; ++r) {
                    float p = __builtin_exp2f(sacc[nt][r]);
                    lrow[r] += p;
                    P[wave][quad*4 + r][nt*16 + l15] = __float2bfloat16(p);
                }
        }

        // ---- O += P V (P per-wave, lgkm-ordered; V frags from swizzled LDS) ----
#pragma unroll
        for (int ks = 0; ks < 2; ++ks) {
            bf16x8 pf = *(const bf16x8*)&P[wave][l15][ks*32 + quad*8];
#pragma unroll
            for (int dt = 0; dt < 8; ++dt) {
                const int dv = dt*16 + l15;
                const int cc = (ks*4 + quad) ^ (l15 & 7);
                bf16x8 vfr = *(const bf16x8*)(&Vsm[cur][0] + dv*64 + cc*8);
                o[dt] = __builtin_amdgcn_mfma_f32_16x16x32_bf16(pf, vfr, o[dt], 0, 0, 0);
            }
        }
    }

    // ---- epilogue: single cross-lane reduce of lrow, normalize, store ----
#pragma unroll
    for (int r = 0; r < 4; ++r) {
        lrow[r] += __shfl_xor(lrow[r], 1);
        lrow[r] += __shfl_xor(lrow[r], 2);
        lrow[r] += __shfl_xor(lrow[r], 4);
        lrow[r] += __shfl_xor(lrow[r], 8);
        float inv = 1.0f / lrow[r];
        int row = ib + quad*4 + r;
#pragma unroll
        for (int dt = 0; dt < 8; ++dt)
            O[(size_t)row*2048 + h*HDIM + dt*16 + l15] = __float2bfloat16(o[dt][r] * inv);
    }
}

// ---------------------------------------------------------------------------
extern "C" void kernel_launch(void* const* d_in, const int* in_sizes, int n_in,
                              void* d_out, int out_size, void* d_ws, size_t ws_size,
                              hipStream_t stream)
{
    (void)in_sizes; (void)n_in; (void)out_size; (void)ws_size;
    const float* hs   = (const float*)d_in[0];
    const float* cosb = (const float*)d_in[1];
    const float* sinb = (const float*)d_in[2];
    const float* Wq   = (const float*)d_in[3];
    const float* Wk   = (const float*)d_in[4];
    const float* Wv   = (const float*)d_in[5];
    const float* Wo   = (const float*)d_in[6];
    const float* qs   = (const float*)d_in[7];
    const float* ks   = (const float*)d_in[8];

    char* ws = (char*)d_ws;
    __hip_bfloat16* WqkvT = (__hip_bfloat16*)(ws);
    __hip_bfloat16* WoT   = (__hip_bfloat16*)(ws + (16u << 20));
    __hip_bfloat16* QKV   = (__hip_bfloat16*)(ws + (24u << 20));
    __hip_bfloat16* Qn    = (__hip_bfloat16*)(ws + (40u << 20));
    __hip_bfloat16* Kn    = (__hip_bfloat16*)(ws + (48u << 20));
    __hip_bfloat16* Vt    = (__hip_bfloat16*)(ws + (52u << 20));
    __hip_bfloat16* hsb   = (__hip_bfloat16*)(ws + (56u << 20)); // overlaid with AT
    __hip_bfloat16* AT    = (__hip_bfloat16*)(ws + (56u << 20)); // disjoint liveness

    trans_cvt_kernel<<<dim3(5120), dim3(256), 0, stream>>>(Wq, Wk, Wv, Wo, hs, WqkvT, WoT, hsb);
    gemm_bt_kernel<__hip_bfloat16><<<dim3(32, 16), dim3(256), 0, stream>>>(hsb, WqkvT, QKV, 2048, 4096, 2048);
    rms_vt_kernel<<<dim3(2560), dim3(256), 0, stream>>>(QKV, cosb, sinb, qs, ks, Qn, Kn, Vt);
    attn_kernel<<<dim3(512), dim3(256), 0, stream>>>(Qn, Kn, Vt, AT);
    gemm_bt64_kernel<float><<<dim3(32, 32), dim3(256), 0, stream>>>(AT, WoT, (float*)d_out, 2048, 2048, 2048);
}